// Round 4
// baseline (6722.073 us; speedup 1.0000x reference)
//
#include <hip/hip_runtime.h>
#include <math.h>

// Problem constants (N,T,V,C,S,CI) = (64,128,25,256,3,64)
constexpr int N_ = 64, T_ = 128, V_ = 25, C_ = 256, S_ = 3;
constexpr int J_ = 384;          // 2*S*CI
constexpr int NT_ = N_ * T_;     // 8192
constexpr int VC_ = V_ * C_;     // 6400
constexpr int SC_ = S_ * C_;     // 768

__device__ __forceinline__ float gelu_f(float x) {
  return 0.5f * x * (1.0f + erff(x * 0.70710678118654752440f));
}
__device__ __forceinline__ float elup1(float x) {  // elu(x)+1
  return x > 0.0f ? x + 1.0f : __expf(x);
}
__device__ __forceinline__ float wave_sum(float x) {
#pragma unroll
  for (int off = 1; off < 64; off <<= 1) x += __shfl_xor(x, off, 64);
  return x;
}
// bf16 storage helpers (storage-only; all math fp32)
__device__ __forceinline__ float bf2f(unsigned short u) {
  union { unsigned int i; float f; } v; v.i = ((unsigned int)u) << 16;
  return v.f;
}
__device__ __forceinline__ unsigned short f2bf(float f) {
  union { float f; unsigned int i; } v; v.f = f;
  unsigned int r = v.i + 0x7fffu + ((v.i >> 16) & 1u);  // RNE
  return (unsigned short)(r >> 16);
}

// MFMA fragment types (verified layout: A row=lane&15, a[j] k=(lane>>4)*8+j;
// B col=lane&15, b[j] same k; C/D col=lane&15, row=(lane>>4)*4+reg)
typedef short bf16x8 __attribute__((ext_vector_type(8)));
typedef float f32x4 __attribute__((ext_vector_type(4)));

// ================= K1: out = bf16(elu(X @ W + b) + 1) ====================
__global__ __launch_bounds__(128) void gemm_in_kernel(
    const float* __restrict__ X, const float* __restrict__ W,
    const float* __restrict__ b, unsigned short* __restrict__ out) {
  __shared__ __align__(16) float xs[VC_];
  const int blk = blockIdx.x;
  const int tid = threadIdx.x;
  const float* Xb = X + (size_t)blk * VC_;
  for (int i = tid; i < VC_; i += 128) xs[i] = Xb[i];
  __syncthreads();
  const int lane = tid & 63, wave = tid >> 6;
  const int nr = wave == 0 ? 13 : 12;
  float acc[13][6];
#pragma unroll
  for (int r = 0; r < 13; ++r)
#pragma unroll
    for (int q = 0; q < 6; ++q) acc[r][q] = 0.f;
#pragma unroll 2
  for (int c = 0; c < C_; ++c) {
    float w[6];
#pragma unroll
    for (int q = 0; q < 6; ++q) w[q] = W[c * J_ + lane + 64 * q];
#pragma unroll
    for (int r = 0; r < 13; ++r) {
      int v = wave + 2 * r;
      float xv = xs[(v < V_ ? v : V_ - 1) * C_ + c];
#pragma unroll
      for (int q = 0; q < 6; ++q) acc[r][q] = fmaf(xv, w[q], acc[r][q]);
    }
  }
  float bj[6];
#pragma unroll
  for (int q = 0; q < 6; ++q) bj[q] = b[lane + 64 * q];
  unsigned short* Ob = out + (size_t)blk * (V_ * J_);
#pragma unroll
  for (int r = 0; r < 13; ++r) {
    int v = wave + 2 * r;
    if (r < nr) {
#pragma unroll
      for (int q = 0; q < 6; ++q)
        Ob[v * J_ + lane + 64 * q] = f2bf(elup1(acc[r][q] + bj[q]));
    }
  }
}

// ============ K2: spatial gram A[n,s,v,u] += sum_{t,c} q*k ===============
// LDS row stride padded 384 -> 390 (mod 32 = 6): k-operand reads across
// pu=0..24 hit >=16 distinct banks (worst 2-way, free).
constexpr int PJ_ = 390;  // padded LDS row stride (floats)
__global__ __launch_bounds__(256) void spatial_A_kernel(
    const unsigned short* __restrict__ QK, float* __restrict__ A) {
  __shared__ __align__(16) float qk[V_ * PJ_];  // 39.0 KB
  const int n = blockIdx.x >> 3, tq = blockIdx.x & 7;
  const int tid = threadIdx.x;
  float acc[3][3];
#pragma unroll
  for (int i = 0; i < 3; ++i)
#pragma unroll
    for (int s = 0; s < 3; ++s) acc[i][s] = 0.f;
  int pv[3], pu[3];
#pragma unroll
  for (int i = 0; i < 3; ++i) {
    int p = tid + 256 * i;
    pv[i] = p / V_;
    pu[i] = p - V_ * pv[i];
  }
  for (int tt = 0; tt < 16; ++tt) {
    int t = tq * 16 + tt;
    const ushort4* src4 =
        (const ushort4*)(QK + (size_t)(n * T_ + t) * (V_ * J_));
    __syncthreads();
    for (int i = tid; i < V_ * J_ / 4; i += 256) {
      int row = i / 96, wi = i - row * 96;  // 96 = J_/4
      ushort4 u = src4[i];
      float* d = qk + row * PJ_ + wi * 4;
      d[0] = bf2f(u.x);
      d[1] = bf2f(u.y);
      d[2] = bf2f(u.z);
      d[3] = bf2f(u.w);
    }
    __syncthreads();
#pragma unroll
    for (int i = 0; i < 3; ++i) {
      if (tid + 256 * i < 625) {
        const float* qr = qk + pv[i] * PJ_;
        const float* kr = qk + pu[i] * PJ_;
        for (int c = 0; c < 64; ++c) {
          float2 q01 = *(const float2*)(qr + c * 6);
          float q2 = qr[c * 6 + 2];
          float k0 = kr[c * 6 + 3];
          float2 k12 = *(const float2*)(kr + c * 6 + 4);
          acc[i][0] = fmaf(q01.x, k0, acc[i][0]);
          acc[i][1] = fmaf(q01.y, k12.x, acc[i][1]);
          acc[i][2] = fmaf(q2, k12.y, acc[i][2]);
        }
      }
    }
  }
#pragma unroll
  for (int i = 0; i < 3; ++i)
    if (tid + 256 * i < 625) {
#pragma unroll
      for (int s = 0; s < 3; ++s)
        atomicAdd(&A[((n * S_ + s) * V_ + pv[i]) * V_ + pu[i]], acc[i][s]);
    }
}

// ======= K3: A = A / rowsum + att0 ========================================
__global__ __launch_bounds__(64) void norm_A_kernel(
    float* __restrict__ A, const float* __restrict__ att0) {
  const int row = blockIdx.x;           // (n*S+s)*V + v
  const int sv = row % (S_ * V_);       // s*V + v
  const int lane = threadIdx.x;
  float val = (lane < V_) ? A[row * V_ + lane] : 0.f;
  float sum = wave_sum(val);
  if (lane < V_) A[row * V_ + lane] = val / sum + att0[sv * V_ + lane];
}

// ====== K4a: y768[nt, v, s, c] = bf16(sum_u A[n,s,v,u] * x[nt,u,c]) ======
__global__ __launch_bounds__(256) void y768_kernel(
    const float* __restrict__ X, const float* __restrict__ A,
    unsigned short* __restrict__ Y768) {
  __shared__ __align__(16) float xs[2 * VC_];      // 51.2 KB
  __shared__ __align__(16) float As[S_ * V_ * 28]; // padded rows
  const int nt0 = blockIdx.x * 2;
  const int n = nt0 >> 7;
  const int tid = threadIdx.x;  // = c
  for (int i = tid; i < 2 * VC_; i += 256)
    xs[i] = X[(size_t)nt0 * VC_ + i];
  const float* Abase = A + n * (S_ * V_ * V_);
  for (int i = tid; i < S_ * V_ * V_; i += 256) {
    int r = i / V_, u = i - r * V_;
    As[r * 28 + u] = Abase[i];
  }
  __syncthreads();
  float xu0[V_], xu1[V_];
#pragma unroll
  for (int u = 0; u < V_; ++u) {
    xu0[u] = xs[u * C_ + tid];
    xu1[u] = xs[VC_ + u * C_ + tid];
  }
  unsigned short* Ob0 = Y768 + (size_t)nt0 * (V_ * SC_);
  unsigned short* Ob1 = Ob0 + (V_ * SC_);
  for (int v = 0; v < V_; ++v) {
#pragma unroll
    for (int s = 0; s < 3; ++s) {
      const float* Ar = As + (s * V_ + v) * 28;
      float a0 = 0.f, a1 = 0.f;
#pragma unroll
      for (int u = 0; u < V_; ++u) {
        float av = Ar[u];
        a0 = fmaf(av, xu0[u], a0);
        a1 = fmaf(av, xu1[u], a1);
      }
      Ob0[(v * S_ + s) * C_ + tid] = f2bf(a0);
      Ob1[(v * S_ + s) * C_ + tid] = f2bf(a1);
    }
  }
}

// ====== K5: weight prep — fragment-major bf16 hi/lo =====================
__global__ __launch_bounds__(256) void prep_w_kernel(
    const float* __restrict__ W, int nS, unsigned short* __restrict__ hi,
    unsigned short* __restrict__ lo) {
  int idx = blockIdx.x * 256 + threadIdx.x;
  int j = idx & 7, l = (idx >> 3) & 63, nfg = (idx >> 9) & 15,
      kstep = (idx >> 13) & 7, s = idx >> 16;
  int col = nfg * 16 + (l & 15);
  int k = kstep * 32 + (l >> 4) * 8 + j;
  float v = W[(k * nS + s) * 256 + col];
  unsigned short h = f2bf(v);
  hi[idx] = h;
  lo[idx] = f2bf(v - bf2f(h));
}

// ====== MFMA projection kernel (8 waves / 512 threads) ===================
// MODE 0: spatial_out  g=gelu(X+ln(Y768@Wo+bo)); out=gelu(X+ln(g@Wf+bf)) f32
// MODE 1: proj_f       out = bf16(ln(Z@Wo+bo))
// MODE 2: proj_final_b g=gelu(Y+Pf+ln(Z@Wo+bo)); out=gelu(Y+ln(g@Wt+bt)) f32
// Latency fix (r4): even/odd register double-buffer for B fragments (loads
// for step k+1 issue before MFMAs of step k); GEMM2's first B loads issued
// before epilogue-1 so LN stats hide them; launch_bounds(512,4) caps VGPR
// at 128 -> 2 blocks/CU so staging stalls are covered by the peer block.
#define LOADB_(dh, dl, Wh, Wl, sk)                                         \
  {                                                                        \
    _Pragma("unroll") for (int nf_ = 0; nf_ < 4; ++nf_) {                  \
      int wo_ = ((sk) * 16 + (wc * 4 + nf_)) * 512 + lane * 8;             \
      dh[nf_] = *(const bf16x8*)((Wh) + wo_);                              \
      dl[nf_] = *(const bf16x8*)((Wl) + wo_);                              \
    }                                                                      \
  }

#define MFMA1_(ks, BH, BL)                                                 \
  {                                                                        \
    bf16x8 af_[2];                                                         \
    _Pragma("unroll") for (int m_ = 0; m_ < 2; ++m_)                       \
        af_[m_] = *(const bf16x8*)&Ash[(((ks) * 4 + (wr * 2 + m_)) * 64 +  \
                                        lane) * 8];                        \
    _Pragma("unroll") for (int nf_ = 0; nf_ < 4; ++nf_) {                  \
      _Pragma("unroll") for (int m_ = 0; m_ < 2; ++m_) {                   \
        acc[m_][nf_] = __builtin_amdgcn_mfma_f32_16x16x32_bf16(            \
            af_[m_], BH[nf_], acc[m_][nf_], 0, 0, 0);                      \
        acc[m_][nf_] = __builtin_amdgcn_mfma_f32_16x16x32_bf16(            \
            af_[m_], BL[nf_], acc[m_][nf_], 0, 0, 0);                      \
      }                                                                    \
    }                                                                      \
  }

#define MFMA2_(ks, BH, BL)                                                 \
  {                                                                        \
    bf16x8 af_[2];                                                         \
    _Pragma("unroll") for (int m_ = 0; m_ < 2; ++m_) {                     \
      int row_ = wr * 32 + m_ * 16 + (lane & 15);                          \
      int slot_ = ((ks) * 4 + (lane >> 4)) ^ (row_ & 7);                   \
      af_[m_] =                                                            \
          *(const bf16x8*)((const char*)Gsh + row_ * 512 + slot_ * 16);    \
    }                                                                      \
    _Pragma("unroll") for (int nf_ = 0; nf_ < 4; ++nf_) {                  \
      _Pragma("unroll") for (int m_ = 0; m_ < 2; ++m_) {                   \
        acc[m_][nf_] = __builtin_amdgcn_mfma_f32_16x16x32_bf16(            \
            af_[m_], BH[nf_], acc[m_][nf_], 0, 0, 0);                      \
        acc[m_][nf_] = __builtin_amdgcn_mfma_f32_16x16x32_bf16(            \
            af_[m_], BL[nf_], acc[m_][nf_], 0, 0, 0);                      \
      }                                                                    \
    }                                                                      \
  }

template <int MODE>
__global__ __launch_bounds__(512, 4) void mfma_proj_kernel(
    const unsigned short* __restrict__ A,    // bf16 GEMM1 input
    const unsigned short* __restrict__ W1h, const unsigned short* __restrict__ W1l,
    const float* __restrict__ b1,
    const float* __restrict__ Res,           // fp32 residual (X or y2)
    const unsigned short* __restrict__ Pf,   // bf16 (MODE 2)
    const unsigned short* __restrict__ W2h, const unsigned short* __restrict__ W2l,
    const float* __restrict__ b2,
    float* __restrict__ OutF,                // MODE 0/2
    unsigned short* __restrict__ OutB) {     // MODE 1
  __shared__ __align__(16) unsigned short Ash[8 * 4 * 64 * 8];  // 32 KB; reused as G
  __shared__ __align__(16) float Red[64][8];                    // 2 KB LN partials
  unsigned short* Gsh = Ash;
  const int tid = threadIdx.x, lane = tid & 63, w = tid >> 6;
  const int wr = w >> 2, wc = w & 3;
  const int bid = blockIdx.x;
  const int n = bid / 50, mt = bid - n * 50;
  const int row0 = n * 3200 + mt * 64;  // flat row (nt*25+v) for Res/Pf/Out
  size_t abase, asstride;
  int arstride;
  if (MODE == 0) {  // Y768: [flat_row][s*256 + c], row stride 768
    abase = (size_t)row0 * 768; arstride = 768; asstride = 256;
  } else {          // Z: [n][s][flat_tv][c]
    abase = (size_t)n * ((size_t)S_ * T_ * VC_) + (size_t)(mt * 64) * 256;
    arstride = 256; asstride = (size_t)T_ * VC_;
  }

  f32x4 acc[2][4];
#pragma unroll
  for (int m = 0; m < 2; ++m)
#pragma unroll
    for (int nf = 0; nf < 4; ++nf) acc[m][nf] = (f32x4){0.f, 0.f, 0.f, 0.f};

  bf16x8 bh0[4], bl0[4], bh1[4], bl1[4];
  LOADB_(bh0, bl0, W1h, W1l, 0);

  // ---------------- GEMM1: K = 768 (3 s-slabs of 256) ----------------
  for (int s = 0; s < 3; ++s) {
    int4 streg[4];
#pragma unroll
    for (int i = 0; i < 4; ++i) {
      int ck = w * 4 + i, ks = ck >> 2, mg = ck & 3;
      int row = mg * 16 + (lane & 15);
      int koff = ks * 32 + (lane >> 4) * 8;
      streg[i] = *(const int4*)(A + abase + (size_t)s * asstride +
                                (size_t)row * arstride + koff);
    }
    __syncthreads();  // readers of previous slab done
#pragma unroll
    for (int i = 0; i < 4; ++i)
      *(int4*)&Ash[((w * 4 + i) * 64 + lane) * 8] = streg[i];
    __syncthreads();
#pragma unroll
    for (int k2 = 0; k2 < 4; ++k2) {
      const int ks = 2 * k2;
      LOADB_(bh1, bl1, W1h, W1l, s * 8 + ks + 1);
      MFMA1_(ks, bh0, bl0);
      if (s * 8 + ks + 2 < 24) LOADB_(bh0, bl0, W1h, W1l, s * 8 + ks + 2);
      MFMA1_(ks + 1, bh1, bl1);
    }
  }
  // prefetch GEMM2's first B fragments; epilogue-1 hides the latency
  if constexpr (MODE != 1) LOADB_(bh0, bl0, W2h, W2l, 0);

  // ---------------- Epilogue 1: per-row LayerNorm stats ----------------
  float b1c[4];
#pragma unroll
  for (int nf = 0; nf < 4; ++nf) b1c[nf] = b1[wc * 64 + nf * 16 + (lane & 15)];
  float s1v[2][4], s2v[2][4];
#pragma unroll
  for (int m = 0; m < 2; ++m)
#pragma unroll
    for (int r = 0; r < 4; ++r) {
      float su = 0.f, sq = 0.f;
#pragma unroll
      for (int nf = 0; nf < 4; ++nf) {
        float v = acc[m][nf][r] + b1c[nf];
        su += v; sq += v * v;
      }
#pragma unroll
      for (int off = 1; off < 16; off <<= 1) {
        su += __shfl_xor(su, off, 64);
        sq += __shfl_xor(sq, off, 64);
      }
      s1v[m][r] = su; s2v[m][r] = sq;
    }
  if ((lane & 15) == 0) {
#pragma unroll
    for (int m = 0; m < 2; ++m)
#pragma unroll
      for (int r = 0; r < 4; ++r) {
        int row = wr * 32 + m * 16 + (lane >> 4) * 4 + r;
        Red[row][2 * wc + 0] = s1v[m][r];
        Red[row][2 * wc + 1] = s2v[m][r];
      }
  }
  __syncthreads();
  float muv[2][4], rsv[2][4];
#pragma unroll
  for (int m = 0; m < 2; ++m)
#pragma unroll
    for (int r = 0; r < 4; ++r) {
      int row = wr * 32 + m * 16 + (lane >> 4) * 4 + r;
      f32x4 p0 = *(const f32x4*)&Red[row][0];
      f32x4 p1 = *(const f32x4*)&Red[row][4];
      float su = p0.x + p0.z + p1.x + p1.z;
      float sq = p0.y + p0.w + p1.y + p1.w;
      float mu = su * (1.f / 256.f);
      float var = fmaxf(sq * (1.f / 256.f) - mu * mu, 0.f);
      muv[m][r] = mu;
      rsv[m][r] = rsqrtf(var + 1e-5f);
    }

  if (MODE == 1) {  // proj_f: out = bf16(ln(vals))
#pragma unroll
    for (int m = 0; m < 2; ++m)
#pragma unroll
      for (int nf = 0; nf < 4; ++nf)
#pragma unroll
        for (int r = 0; r < 4; ++r) {
          int row = wr * 32 + m * 16 + (lane >> 4) * 4 + r;
          int col = wc * 64 + nf * 16 + (lane & 15);
          OutB[(size_t)(row0 + row) * 256 + col] =
              f2bf((acc[m][nf][r] + b1c[nf] - muv[m][r]) * rsv[m][r]);
        }
    return;
  }

  // g = gelu(res [+pf] + ln(vals)) -> bf16 in XOR-swizzled LDS (reuses Ash)
#pragma unroll
  for (int m = 0; m < 2; ++m)
#pragma unroll
    for (int nf = 0; nf < 4; ++nf)
#pragma unroll
      for (int r = 0; r < 4; ++r) {
        int row = wr * 32 + m * 16 + (lane >> 4) * 4 + r;
        int col = wc * 64 + nf * 16 + (lane & 15);
        float resv = Res[(size_t)(row0 + row) * 256 + col];
        if (MODE == 2) resv += bf2f(Pf[(size_t)(row0 + row) * 256 + col]);
        float gv = gelu_f(resv + (acc[m][nf][r] + b1c[nf] - muv[m][r]) * rsv[m][r]);
        int slot = (col >> 3) ^ (row & 7);
        *(unsigned short*)((char*)Gsh + row * 512 + slot * 16 + (col & 7) * 2) =
            f2bf(gv);
      }
  __syncthreads();

  // ---------------- GEMM2: K = 256 from Gsh ----------------
#pragma unroll
  for (int m = 0; m < 2; ++m)
#pragma unroll
    for (int nf = 0; nf < 4; ++nf) acc[m][nf] = (f32x4){0.f, 0.f, 0.f, 0.f};
#pragma unroll
  for (int k2 = 0; k2 < 4; ++k2) {
    const int ks = 2 * k2;
    LOADB_(bh1, bl1, W2h, W2l, ks + 1);
    MFMA2_(ks, bh0, bl0);
    if (ks + 2 < 8) LOADB_(bh0, bl0, W2h, W2l, ks + 2);
    MFMA2_(ks + 1, bh1, bl1);
  }

  // ---------------- Epilogue 2 ----------------
  float b2c[4];
#pragma unroll
  for (int nf = 0; nf < 4; ++nf) b2c[nf] = b2[wc * 64 + nf * 16 + (lane & 15)];
#pragma unroll
  for (int m = 0; m < 2; ++m)
#pragma unroll
    for (int r = 0; r < 4; ++r) {
      float su = 0.f, sq = 0.f;
#pragma unroll
      for (int nf = 0; nf < 4; ++nf) {
        float v = acc[m][nf][r] + b2c[nf];
        su += v; sq += v * v;
      }
#pragma unroll
      for (int off = 1; off < 16; off <<= 1) {
        su += __shfl_xor(su, off, 64);
        sq += __shfl_xor(sq, off, 64);
      }
      s1v[m][r] = su; s2v[m][r] = sq;
    }
  if ((lane & 15) == 0) {
#pragma unroll
    for (int m = 0; m < 2; ++m)
#pragma unroll
      for (int r = 0; r < 4; ++r) {
        int row = wr * 32 + m * 16 + (lane >> 4) * 4 + r;
        Red[row][2 * wc + 0] = s1v[m][r];
        Red[row][2 * wc + 1] = s2v[m][r];
      }
  }
  __syncthreads();
#pragma unroll
  for (int m = 0; m < 2; ++m)
#pragma unroll
    for (int r = 0; r < 4; ++r) {
      int row = wr * 32 + m * 16 + (lane >> 4) * 4 + r;
      f32x4 p0 = *(const f32x4*)&Red[row][0];
      f32x4 p1 = *(const f32x4*)&Red[row][4];
      float su = p0.x + p0.z + p1.x + p1.z;
      float sq = p0.y + p0.w + p1.y + p1.w;
      float mu = su * (1.f / 256.f);
      float var = fmaxf(sq * (1.f / 256.f) - mu * mu, 0.f);
      muv[m][r] = mu;
      rsv[m][r] = rsqrtf(var + 1e-5f);
    }
#pragma unroll
  for (int m = 0; m < 2; ++m)
#pragma unroll
    for (int nf = 0; nf < 4; ++nf)
#pragma unroll
      for (int r = 0; r < 4; ++r) {
        int row = wr * 32 + m * 16 + (lane >> 4) * 4 + r;
        int col = wc * 64 + nf * 16 + (lane & 15);
        float resv = Res[(size_t)(row0 + row) * 256 + col];
        OutF[(size_t)(row0 + row) * 256 + col] =
            gelu_f(resv + (acc[m][nf][r] + b2c[nf] - muv[m][r]) * rsv[m][r]);
      }
}

// ====== K6: Af[n,s,t,k] = sum_{v,c} q[t]*k[k]  (unnormalized) ============
__global__ __launch_bounds__(256) void temporal_A_kernel(
    const unsigned short* __restrict__ QK, float* __restrict__ A) {
  __shared__ __align__(16) float Qs[32 * 68];
  __shared__ __align__(16) float Ks[128 * 68];
  const int tt = blockIdx.x, s = blockIdx.y, n = blockIdx.z;
  const int tid = threadIdx.x;
  const int kg = tid & 15;   // k = kg + 16*j
  const int tp = tid >> 4;   // rows tp*2, tp*2+1
  float acc[2][8];
#pragma unroll
  for (int r = 0; r < 2; ++r)
#pragma unroll
    for (int j = 0; j < 8; ++j) acc[r][j] = 0.f;
  for (int v = 0; v < V_; ++v) {
    __syncthreads();
    for (int i = tid; i < 128 * 64; i += 256) {
      int k = i >> 6, c = i & 63;
      Ks[k * 68 + c] =
          bf2f(QK[(size_t)((n * T_ + k) * V_ + v) * J_ + c * 6 + 3 + s]);
    }
    for (int i = tid; i < 32 * 64; i += 256) {
      int t = i >> 6, c = i & 63;
      Qs[t * 68 + c] =
          bf2f(QK[(size_t)((n * T_ + tt * 32 + t) * V_ + v) * J_ + c * 6 + s]);
    }
    __syncthreads();
    for (int c = 0; c < 64; c += 4) {
      float4 q0 = *(const float4*)(Qs + (tp * 2 + 0) * 68 + c);
      float4 q1 = *(const float4*)(Qs + (tp * 2 + 1) * 68 + c);
#pragma unroll
      for (int j = 0; j < 8; ++j) {
        float4 kv = *(const float4*)(Ks + (kg + 16 * j) * 68 + c);
        acc[0][j] = fmaf(q0.x, kv.x, fmaf(q0.y, kv.y,
                    fmaf(q0.z, kv.z, fmaf(q0.w, kv.w, acc[0][j]))));
        acc[1][j] = fmaf(q1.x, kv.x, fmaf(q1.y, kv.y,
                    fmaf(q1.z, kv.z, fmaf(q1.w, kv.w, acc[1][j]))));
      }
    }
  }
  float* Ob = A + ((size_t)(n * S_ + s) * T_ + tt * 32) * T_;
#pragma unroll
  for (int r = 0; r < 2; ++r)
#pragma unroll
    for (int j = 0; j < 8; ++j)
      Ob[(tp * 2 + r) * T_ + kg + 16 * j] = acc[r][j];
}

// ====== K6b: mask (tril/triu) + row-normalize Af and Ab ==================
__global__ __launch_bounds__(64) void norm_temporal_kernel(
    float* __restrict__ Af, float* __restrict__ Ab) {
  const int row = blockIdx.x;  // (n*S+s)*T + t
  const int t = row & (T_ - 1);
  const int lane = threadIdx.x;
  float* A = blockIdx.y == 0 ? Af : Ab;
  const bool fw = blockIdx.y == 0;
  float v0 = A[(size_t)row * T_ + lane];
  float v1 = A[(size_t)row * T_ + lane + 64];
  v0 *= fw ? (lane <= t ? 1.f : 0.f) : (lane >= t ? 1.f : 0.f);
  v1 *= fw ? (lane + 64 <= t ? 1.f : 0.f) : (lane + 64 >= t ? 1.f : 0.f);
  float inv = 1.f / wave_sum(v0 + v1);
  A[(size_t)row * T_ + lane] = v0 * inv;
  A[(size_t)row * T_ + lane + 64] = v1 * inv;
}

// ====== K7: Z[n,s,t,vc] = bf16(sum_k A[n,s,t,k] * Y[n,k,vc]) — MFMA ======
__global__ __launch_bounds__(256, 3) void temporal_z_mfma_kernel(
    const float* __restrict__ A, const float* __restrict__ Y,
    unsigned short* __restrict__ Z) {
  __shared__ __align__(16) unsigned short Ahs[4 * 4 * 64 * 8];  // 16 KB
  __shared__ __align__(16) unsigned short Als[4 * 4 * 64 * 8];  // 16 KB
  __shared__ __align__(16) unsigned short Ys[16 * 64 * 8];      // 16 KB
  const int cb = blockIdx.x;                     // col block of 256
  const int s = blockIdx.y >> 1, rt = blockIdx.y & 1;
  const int n = blockIdx.z;
  const int tid = threadIdx.x, lane = tid & 63, w = tid >> 6;
  const int t0 = rt * 64;
  const float* Atile = A + ((size_t)(n * S_ + s) * T_ + t0) * T_;  // 64x128
  // convert A tile to frag-major bf16 hi/lo
  for (int i = tid; i < 64 * 128; i += 256) {
    int r = i >> 7, k = i & 127;
    float av = Atile[r * T_ + k];
    unsigned short h = f2bf(av);
    unsigned short l = f2bf(av - bf2f(h));
    int idx = ((((k >> 5) * 4 + (r >> 4)) * 64 + (r & 15) + 16 * ((k >> 3) & 3))
               << 3) | (k & 7);
    Ahs[idx] = h;
    Als[idx] = l;
  }
  f32x4 acc[4][4];
#pragma unroll
  for (int m = 0; m < 4; ++m)
#pragma unroll
    for (int nf = 0; nf < 4; ++nf) acc[m][nf] = (f32x4){0.f, 0.f, 0.f, 0.f};
  const float* Yb = Y + (size_t)n * (T_ * VC_) + cb * 256;
  for (int kstep = 0; kstep < 4; ++kstep) {
    __syncthreads();  // A-conversion done (iter 0) / prior Ys reads done
    for (int i = tid; i < 32 * 256; i += 256) {
      int kl = i >> 8, c = i & 255;
      float yv = Yb[(size_t)(kstep * 32 + kl) * VC_ + c];
      Ys[(((c >> 4) * 64 + (c & 15) + 16 * ((kl >> 3) & 3)) << 3) | (kl & 7)] =
          f2bf(yv);
    }
    __syncthreads();
    bf16x8 bv[4];
#pragma unroll
    for (int nf = 0; nf < 4; ++nf)
      bv[nf] = *(const bf16x8*)&Ys[((w * 4 + nf) * 64 + lane) * 8];
    bf16x8 af[4];
#pragma unroll
    for (int m = 0; m < 4; ++m)
      af[m] = *(const bf16x8*)&Ahs[((kstep * 4 + m) * 64 + lane) * 8];
#pragma unroll
    for (int nf = 0; nf < 4; ++nf)
#pragma unroll
      for (int m = 0; m < 4; ++m)
        acc[m][nf] = __builtin_amdgcn_mfma_f32_16x16x32_bf16(af[m], bv[nf], acc[m][nf], 0, 0, 0);
#pragma unroll
    for (int m = 0; m < 4; ++m)
      af[m] = *(const bf16x8*)&Als[((kstep * 4 + m) * 64 + lane) * 8];
#pragma unroll
    for (int nf = 0; nf < 4; ++nf)
#pragma unroll
      for (int m = 0; m < 4; ++m)
        acc[m][nf] = __builtin_amdgcn_mfma_f32_16x16x32_bf16(af[m], bv[nf], acc[m][nf], 0, 0, 0);
  }
  unsigned short* Zb = Z + ((size_t)(n * S_ + s) * T_ + t0) * VC_ + cb * 256;
#pragma unroll
  for (int m = 0; m < 4; ++m)
#pragma unroll
    for (int nf = 0; nf < 4; ++nf)
#pragma unroll
      for (int r = 0; r < 4; ++r) {
        int trow = m * 16 + (lane >> 4) * 4 + r;
        int col = w * 64 + nf * 16 + (lane & 15);
        Zb[(size_t)trow * VC_ + col] = f2bf(acc[m][nf][r]);
      }
}

extern "C" void kernel_launch(void* const* d_in, const int* in_sizes, int n_in,
                              void* d_out, int out_size, void* d_ws,
                              size_t ws_size, hipStream_t stream) {
  const float* x      = (const float*)d_in[0];
  const float* W_ins  = (const float*)d_in[1];
  const float* b_ins  = (const float*)d_in[2];
  const float* att0   = (const float*)d_in[3];
  const float* W_outs = (const float*)d_in[4];
  const float* b_outs = (const float*)d_in[5];
  const float* W_ffs  = (const float*)d_in[6];
  const float* b_ffs  = (const float*)d_in[7];
  const float* W_inf  = (const float*)d_in[8];
  const float* b_inf  = (const float*)d_in[9];
  const float* W_inb  = (const float*)d_in[10];
  const float* b_inb  = (const float*)d_in[11];
  const float* W_outf = (const float*)d_in[12];
  const float* b_outf = (const float*)d_in[13];
  const float* W_outb = (const float*)d_in[14];
  const float* b_outb = (const float*)d_in[15];
  const float* W_fft  = (const float*)d_in[16];
  const float* b_fft  = (const float*)d_in[17];
  float* out = (float*)d_out;
  char* base = (char*)d_ws;

  // Workspace layout (bytes). Peak = 657,675,008 B ≈ 627.2 MiB.
  unsigned short* B0    = (unsigned short*)base;
  float*          y2    = (float*)(base + 314572800);           // 209.7 MB fp32
  unsigned short* projf = (unsigned short*)(base + 524288000);  // 104.9 MB bf16
  float*          Asp   = (float*)(base + 629145600);           // 0.48 MB
  float*          Af    = (float*)(base + 629625600);           // 12.6 MB
  float*          Ab    = (float*)(base + 642208512);           // 12.6 MB
  unsigned short* Wouts_h = (unsigned short*)(base + 654791424);
  unsigned short* Wouts_l = (unsigned short*)(base + 655184640);
  unsigned short* Wffs_h  = (unsigned short*)(base + 655577856);
  unsigned short* Wffs_l  = (unsigned short*)(base + 655708928);
  unsigned short* Woutf_h = (unsigned short*)(base + 655840000);
  unsigned short* Woutf_l = (unsigned short*)(base + 656233216);
  unsigned short* Woutb_h = (unsigned short*)(base + 656626432);
  unsigned short* Woutb_l = (unsigned short*)(base + 657019648);
  unsigned short* Wfft_h  = (unsigned short*)(base + 657412864);
  unsigned short* Wfft_l  = (unsigned short*)(base + 657543936);

  unsigned short* QKs  = B0;
  unsigned short* Y768 = B0;
  unsigned short* QKf  = B0;
  unsigned short* QKb  = B0 + 78643200;
  unsigned short* Zbuf = B0;

  // ---- weight prep (fragment-major bf16 hi/lo) ----
  prep_w_kernel<<<768, 256, 0, stream>>>(W_outs, 3, Wouts_h, Wouts_l);
  prep_w_kernel<<<256, 256, 0, stream>>>(W_ffs, 1, Wffs_h, Wffs_l);
  prep_w_kernel<<<768, 256, 0, stream>>>(W_outf, 3, Woutf_h, Woutf_l);
  prep_w_kernel<<<768, 256, 0, stream>>>(W_outb, 3, Woutb_h, Woutb_l);
  prep_w_kernel<<<256, 256, 0, stream>>>(W_fft, 1, Wfft_h, Wfft_l);

  // ---- spatial stage ----
  gemm_in_kernel<<<NT_, 128, 0, stream>>>(x, W_ins, b_ins, QKs);
  hipMemsetAsync(Asp, 0, (size_t)N_ * S_ * V_ * V_ * sizeof(float), stream);
  spatial_A_kernel<<<N_ * 8, 256, 0, stream>>>(QKs, Asp);
  norm_A_kernel<<<N_ * S_ * V_, 64, 0, stream>>>(Asp, att0);
  y768_kernel<<<NT_ / 2, 256, 0, stream>>>(x, Asp, Y768);
  mfma_proj_kernel<0><<<3200, 512, 0, stream>>>(
      Y768, Wouts_h, Wouts_l, b_outs, x, nullptr, Wffs_h, Wffs_l, b_ffs, y2,
      nullptr);
  // ---- temporal stage ----
  gemm_in_kernel<<<NT_, 128, 0, stream>>>(y2, W_inf, b_inf, QKf);
  gemm_in_kernel<<<NT_, 128, 0, stream>>>(y2, W_inb, b_inb, QKb);
  temporal_A_kernel<<<dim3(4, 3, 64), 256, 0, stream>>>(QKf, Af);
  temporal_A_kernel<<<dim3(4, 3, 64), 256, 0, stream>>>(QKb, Ab);
  norm_temporal_kernel<<<dim3(N_ * S_ * T_, 2), 64, 0, stream>>>(Af, Ab);
  // forward: Zf -> projf (Zbuf overlays dead QKf/QKb)
  temporal_z_mfma_kernel<<<dim3(25, 6, 64), 256, 0, stream>>>(Af, y2, Zbuf);
  mfma_proj_kernel<1><<<3200, 512, 0, stream>>>(
      Zbuf, Woutf_h, Woutf_l, b_outf, nullptr, nullptr, nullptr, nullptr,
      nullptr, nullptr, projf);
  // backward: Zb -> fused projection + final output
  temporal_z_mfma_kernel<<<dim3(25, 6, 64), 256, 0, stream>>>(Ab, y2, Zbuf);
  mfma_proj_kernel<2><<<3200, 512, 0, stream>>>(
      Zbuf, Woutb_h, Woutb_l, b_outb, y2, projf, Wfft_h, Wfft_l, b_fft, out,
      nullptr);
}

// Round 5
// 5543.615 us; speedup vs baseline: 1.2126x; 1.2126x over previous
//
#include <hip/hip_runtime.h>
#include <math.h>

// Problem constants (N,T,V,C,S,CI) = (64,128,25,256,3,64)
constexpr int N_ = 64, T_ = 128, V_ = 25, C_ = 256, S_ = 3;
constexpr int J_ = 384;          // 2*S*CI
constexpr int NT_ = N_ * T_;     // 8192
constexpr int VC_ = V_ * C_;     // 6400
constexpr int SC_ = S_ * C_;     // 768

__device__ __forceinline__ float gelu_f(float x) {
  return 0.5f * x * (1.0f + erff(x * 0.70710678118654752440f));
}
__device__ __forceinline__ float elup1(float x) {  // elu(x)+1
  return x > 0.0f ? x + 1.0f : __expf(x);
}
__device__ __forceinline__ float wave_sum(float x) {
#pragma unroll
  for (int off = 1; off < 64; off <<= 1) x += __shfl_xor(x, off, 64);
  return x;
}
// bf16 storage helpers (storage-only; all math fp32)
__device__ __forceinline__ float bf2f(unsigned short u) {
  union { unsigned int i; float f; } v; v.i = ((unsigned int)u) << 16;
  return v.f;
}
__device__ __forceinline__ unsigned short f2bf(float f) {
  union { float f; unsigned int i; } v; v.f = f;
  unsigned int r = v.i + 0x7fffu + ((v.i >> 16) & 1u);  // RNE
  return (unsigned short)(r >> 16);
}

// MFMA fragment types (verified layout: A row=lane&15, a[j] k=(lane>>4)*8+j;
// B col=lane&15, b[j] same k; C/D col=lane&15, row=(lane>>4)*4+reg)
typedef short bf16x8 __attribute__((ext_vector_type(8)));
typedef float f32x4 __attribute__((ext_vector_type(4)));

// ================= K1: out = bf16(elu(X @ W + b) + 1) ====================
__global__ __launch_bounds__(128) void gemm_in_kernel(
    const float* __restrict__ X, const float* __restrict__ W,
    const float* __restrict__ b, unsigned short* __restrict__ out) {
  __shared__ __align__(16) float xs[VC_];
  const int blk = blockIdx.x;
  const int tid = threadIdx.x;
  const float* Xb = X + (size_t)blk * VC_;
  for (int i = tid; i < VC_; i += 128) xs[i] = Xb[i];
  __syncthreads();
  const int lane = tid & 63, wave = tid >> 6;
  const int nr = wave == 0 ? 13 : 12;
  float acc[13][6];
#pragma unroll
  for (int r = 0; r < 13; ++r)
#pragma unroll
    for (int q = 0; q < 6; ++q) acc[r][q] = 0.f;
#pragma unroll 2
  for (int c = 0; c < C_; ++c) {
    float w[6];
#pragma unroll
    for (int q = 0; q < 6; ++q) w[q] = W[c * J_ + lane + 64 * q];
#pragma unroll
    for (int r = 0; r < 13; ++r) {
      int v = wave + 2 * r;
      float xv = xs[(v < V_ ? v : V_ - 1) * C_ + c];
#pragma unroll
      for (int q = 0; q < 6; ++q) acc[r][q] = fmaf(xv, w[q], acc[r][q]);
    }
  }
  float bj[6];
#pragma unroll
  for (int q = 0; q < 6; ++q) bj[q] = b[lane + 64 * q];
  unsigned short* Ob = out + (size_t)blk * (V_ * J_);
#pragma unroll
  for (int r = 0; r < 13; ++r) {
    int v = wave + 2 * r;
    if (r < nr) {
#pragma unroll
      for (int q = 0; q < 6; ++q)
        Ob[v * J_ + lane + 64 * q] = f2bf(elup1(acc[r][q] + bj[q]));
    }
  }
}

// ============ K2: spatial gram A[n,s,v,u] += sum_{t,c} q*k ===============
// LDS row stride padded 384 -> 390 (mod 32 = 6): k-operand reads across
// pu=0..24 hit >=16 distinct banks (worst 2-way, free).
constexpr int PJ_ = 390;  // padded LDS row stride (floats)
__global__ __launch_bounds__(256) void spatial_A_kernel(
    const unsigned short* __restrict__ QK, float* __restrict__ A) {
  __shared__ __align__(16) float qk[V_ * PJ_];  // 39.0 KB
  const int n = blockIdx.x >> 3, tq = blockIdx.x & 7;
  const int tid = threadIdx.x;
  float acc[3][3];
#pragma unroll
  for (int i = 0; i < 3; ++i)
#pragma unroll
    for (int s = 0; s < 3; ++s) acc[i][s] = 0.f;
  int pv[3], pu[3];
#pragma unroll
  for (int i = 0; i < 3; ++i) {
    int p = tid + 256 * i;
    pv[i] = p / V_;
    pu[i] = p - V_ * pv[i];
  }
  for (int tt = 0; tt < 16; ++tt) {
    int t = tq * 16 + tt;
    const ushort4* src4 =
        (const ushort4*)(QK + (size_t)(n * T_ + t) * (V_ * J_));
    __syncthreads();
    for (int i = tid; i < V_ * J_ / 4; i += 256) {
      int row = i / 96, wi = i - row * 96;  // 96 = J_/4
      ushort4 u = src4[i];
      float* d = qk + row * PJ_ + wi * 4;
      d[0] = bf2f(u.x);
      d[1] = bf2f(u.y);
      d[2] = bf2f(u.z);
      d[3] = bf2f(u.w);
    }
    __syncthreads();
#pragma unroll
    for (int i = 0; i < 3; ++i) {
      if (tid + 256 * i < 625) {
        const float* qr = qk + pv[i] * PJ_;
        const float* kr = qk + pu[i] * PJ_;
        for (int c = 0; c < 64; ++c) {
          float2 q01 = *(const float2*)(qr + c * 6);
          float q2 = qr[c * 6 + 2];
          float k0 = kr[c * 6 + 3];
          float2 k12 = *(const float2*)(kr + c * 6 + 4);
          acc[i][0] = fmaf(q01.x, k0, acc[i][0]);
          acc[i][1] = fmaf(q01.y, k12.x, acc[i][1]);
          acc[i][2] = fmaf(q2, k12.y, acc[i][2]);
        }
      }
    }
  }
#pragma unroll
  for (int i = 0; i < 3; ++i)
    if (tid + 256 * i < 625) {
#pragma unroll
      for (int s = 0; s < 3; ++s)
        atomicAdd(&A[((n * S_ + s) * V_ + pv[i]) * V_ + pu[i]], acc[i][s]);
    }
}

// ======= K3: A = A / rowsum + att0 ========================================
__global__ __launch_bounds__(64) void norm_A_kernel(
    float* __restrict__ A, const float* __restrict__ att0) {
  const int row = blockIdx.x;           // (n*S+s)*V + v
  const int sv = row % (S_ * V_);       // s*V + v
  const int lane = threadIdx.x;
  float val = (lane < V_) ? A[row * V_ + lane] : 0.f;
  float sum = wave_sum(val);
  if (lane < V_) A[row * V_ + lane] = val / sum + att0[sv * V_ + lane];
}

// ====== K4a: y768[nt, v, s, c] = bf16(sum_u A[n,s,v,u] * x[nt,u,c]) ======
__global__ __launch_bounds__(256) void y768_kernel(
    const float* __restrict__ X, const float* __restrict__ A,
    unsigned short* __restrict__ Y768) {
  __shared__ __align__(16) float xs[2 * VC_];      // 51.2 KB
  __shared__ __align__(16) float As[S_ * V_ * 28]; // padded rows
  const int nt0 = blockIdx.x * 2;
  const int n = nt0 >> 7;
  const int tid = threadIdx.x;  // = c
  for (int i = tid; i < 2 * VC_; i += 256)
    xs[i] = X[(size_t)nt0 * VC_ + i];
  const float* Abase = A + n * (S_ * V_ * V_);
  for (int i = tid; i < S_ * V_ * V_; i += 256) {
    int r = i / V_, u = i - r * V_;
    As[r * 28 + u] = Abase[i];
  }
  __syncthreads();
  float xu0[V_], xu1[V_];
#pragma unroll
  for (int u = 0; u < V_; ++u) {
    xu0[u] = xs[u * C_ + tid];
    xu1[u] = xs[VC_ + u * C_ + tid];
  }
  unsigned short* Ob0 = Y768 + (size_t)nt0 * (V_ * SC_);
  unsigned short* Ob1 = Ob0 + (V_ * SC_);
  for (int v = 0; v < V_; ++v) {
#pragma unroll
    for (int s = 0; s < 3; ++s) {
      const float* Ar = As + (s * V_ + v) * 28;
      float a0 = 0.f, a1 = 0.f;
#pragma unroll
      for (int u = 0; u < V_; ++u) {
        float av = Ar[u];
        a0 = fmaf(av, xu0[u], a0);
        a1 = fmaf(av, xu1[u], a1);
      }
      Ob0[(v * S_ + s) * C_ + tid] = f2bf(a0);
      Ob1[(v * S_ + s) * C_ + tid] = f2bf(a1);
    }
  }
}

// ====== K5: weight prep — fragment-major bf16 hi/lo =====================
__global__ __launch_bounds__(256) void prep_w_kernel(
    const float* __restrict__ W, int nS, unsigned short* __restrict__ hi,
    unsigned short* __restrict__ lo) {
  int idx = blockIdx.x * 256 + threadIdx.x;
  int j = idx & 7, l = (idx >> 3) & 63, nfg = (idx >> 9) & 15,
      kstep = (idx >> 13) & 7, s = idx >> 16;
  int col = nfg * 16 + (l & 15);
  int k = kstep * 32 + (l >> 4) * 8 + j;
  float v = W[(k * nS + s) * 256 + col];
  unsigned short h = f2bf(v);
  hi[idx] = h;
  lo[idx] = f2bf(v - bf2f(h));
}

// ====== MFMA projection kernel (8 waves / 512 threads) ===================
// MODE 0: spatial_out  g=gelu(X+ln(Y768@Wo+bo)); out=gelu(X+ln(g@Wf+bf)) f32
// MODE 1: proj_f       out = bf16(ln(Z@Wo+bo))
// MODE 2: proj_final_b g=gelu(Y+Pf+ln(Z@Wo+bo)); out=gelu(Y+ln(g@Wt+bt)) f32
// r5: 128-row x 256-col block tile (wave owns 64x64, acc 4x4): 32 MFMAs per
// B-fragment load pair (2x r3's intensity), B L2 traffic halved. Register
// double-buffer for B kept; launch_bounds(512,2) = 256-VGPR budget so the
// dbuf lives in registers (r4's (512,4) cap forced spills: VGPR 64 + 2.5 GB
// scratch HBM traffic -> regression).
#define LOADB_(dh, dl, Wh, Wl, sk)                                         \
  {                                                                        \
    _Pragma("unroll") for (int nf_ = 0; nf_ < 4; ++nf_) {                  \
      int wo_ = ((sk) * 16 + (wc * 4 + nf_)) * 512 + lane * 8;             \
      dh[nf_] = *(const bf16x8*)((Wh) + wo_);                              \
      dl[nf_] = *(const bf16x8*)((Wl) + wo_);                              \
    }                                                                      \
  }

#define MFMA1_(ks, BH, BL)                                                 \
  {                                                                        \
    _Pragma("unroll") for (int m_ = 0; m_ < 4; ++m_) {                     \
      bf16x8 af_ = *(const bf16x8*)&Ash[(((ks) * 8 + (wr * 4 + m_)) * 64 + \
                                         lane) * 8];                       \
      _Pragma("unroll") for (int nf_ = 0; nf_ < 4; ++nf_) {                \
        acc[m_][nf_] = __builtin_amdgcn_mfma_f32_16x16x32_bf16(            \
            af_, BH[nf_], acc[m_][nf_], 0, 0, 0);                          \
        acc[m_][nf_] = __builtin_amdgcn_mfma_f32_16x16x32_bf16(            \
            af_, BL[nf_], acc[m_][nf_], 0, 0, 0);                          \
      }                                                                    \
    }                                                                      \
  }

#define MFMA2_(ks, BH, BL)                                                 \
  {                                                                        \
    _Pragma("unroll") for (int m_ = 0; m_ < 4; ++m_) {                     \
      int row_ = wr * 64 + m_ * 16 + (lane & 15);                          \
      int slot_ = ((ks) * 4 + (lane >> 4)) ^ (row_ & 7);                   \
      bf16x8 af_ =                                                         \
          *(const bf16x8*)((const char*)Gsh + row_ * 512 + slot_ * 16);    \
      _Pragma("unroll") for (int nf_ = 0; nf_ < 4; ++nf_) {                \
        acc[m_][nf_] = __builtin_amdgcn_mfma_f32_16x16x32_bf16(            \
            af_, BH[nf_], acc[m_][nf_], 0, 0, 0);                          \
        acc[m_][nf_] = __builtin_amdgcn_mfma_f32_16x16x32_bf16(            \
            af_, BL[nf_], acc[m_][nf_], 0, 0, 0);                          \
      }                                                                    \
    }                                                                      \
  }

template <int MODE>
__global__ __launch_bounds__(512, 2) void mfma_proj_kernel(
    const unsigned short* __restrict__ A,    // bf16 GEMM1 input
    const unsigned short* __restrict__ W1h, const unsigned short* __restrict__ W1l,
    const float* __restrict__ b1,
    const float* __restrict__ Res,           // fp32 residual (X or y2)
    const unsigned short* __restrict__ Pf,   // bf16 (MODE 2)
    const unsigned short* __restrict__ W2h, const unsigned short* __restrict__ W2l,
    const float* __restrict__ b2,
    float* __restrict__ OutF,                // MODE 0/2
    unsigned short* __restrict__ OutB) {     // MODE 1
  __shared__ __align__(16) unsigned short Ash[8 * 8 * 64 * 8];  // 64 KB; reused as G
  __shared__ __align__(16) float Red[128][8];                   // 4 KB LN partials
  unsigned short* Gsh = Ash;
  const int tid = threadIdx.x, lane = tid & 63, w = tid >> 6;
  const int wr = w >> 2, wc = w & 3;
  const int bid = blockIdx.x;
  const int n = bid / 25, mt = bid - n * 25;
  const int row0 = n * 3200 + mt * 128;  // flat row (nt*25+v) for Res/Pf/Out
  size_t abase, asstride;
  int arstride;
  if (MODE == 0) {  // Y768: [flat_row][s*256 + c], row stride 768
    abase = (size_t)row0 * 768; arstride = 768; asstride = 256;
  } else {          // Z: [n][s][flat_tv][c]
    abase = (size_t)n * ((size_t)S_ * T_ * VC_) + (size_t)(mt * 128) * 256;
    arstride = 256; asstride = (size_t)T_ * VC_;
  }

  f32x4 acc[4][4];
#pragma unroll
  for (int m = 0; m < 4; ++m)
#pragma unroll
    for (int nf = 0; nf < 4; ++nf) acc[m][nf] = (f32x4){0.f, 0.f, 0.f, 0.f};

  bf16x8 bh0[4], bl0[4], bh1[4], bl1[4];
  LOADB_(bh0, bl0, W1h, W1l, 0);

  // ---------------- GEMM1: K = 768 (3 s-slabs of 256) ----------------
  for (int s = 0; s < 3; ++s) {
    int4 streg[8];
#pragma unroll
    for (int i = 0; i < 8; ++i) {
      int ck = w * 8 + i, ks = ck >> 3, mg = ck & 7;
      int row = mg * 16 + (lane & 15);
      int koff = ks * 32 + (lane >> 4) * 8;
      streg[i] = *(const int4*)(A + abase + (size_t)s * asstride +
                                (size_t)row * arstride + koff);
    }
    __syncthreads();  // readers of previous slab done
#pragma unroll
    for (int i = 0; i < 8; ++i)
      *(int4*)&Ash[((w * 8 + i) * 64 + lane) * 8] = streg[i];
    __syncthreads();
#pragma unroll
    for (int k2 = 0; k2 < 4; ++k2) {
      const int ks = 2 * k2;
      LOADB_(bh1, bl1, W1h, W1l, s * 8 + ks + 1);
      MFMA1_(ks, bh0, bl0);
      if (s * 8 + ks + 2 < 24) LOADB_(bh0, bl0, W1h, W1l, s * 8 + ks + 2);
      MFMA1_(ks + 1, bh1, bl1);
    }
  }
  // prefetch GEMM2's first B fragments; epilogue-1 hides the latency
  if constexpr (MODE != 1) LOADB_(bh0, bl0, W2h, W2l, 0);

  // ---------------- Epilogue 1: per-row LayerNorm stats ----------------
  float b1c[4];
#pragma unroll
  for (int nf = 0; nf < 4; ++nf) b1c[nf] = b1[wc * 64 + nf * 16 + (lane & 15)];
  float s1v[4][4], s2v[4][4];
#pragma unroll
  for (int m = 0; m < 4; ++m)
#pragma unroll
    for (int r = 0; r < 4; ++r) {
      float su = 0.f, sq = 0.f;
#pragma unroll
      for (int nf = 0; nf < 4; ++nf) {
        float v = acc[m][nf][r] + b1c[nf];
        su += v; sq += v * v;
      }
#pragma unroll
      for (int off = 1; off < 16; off <<= 1) {
        su += __shfl_xor(su, off, 64);
        sq += __shfl_xor(sq, off, 64);
      }
      s1v[m][r] = su; s2v[m][r] = sq;
    }
  if ((lane & 15) == 0) {
#pragma unroll
    for (int m = 0; m < 4; ++m)
#pragma unroll
      for (int r = 0; r < 4; ++r) {
        int row = wr * 64 + m * 16 + (lane >> 4) * 4 + r;
        Red[row][2 * wc + 0] = s1v[m][r];
        Red[row][2 * wc + 1] = s2v[m][r];
      }
  }
  __syncthreads();
  float muv[4][4], rsv[4][4];
#pragma unroll
  for (int m = 0; m < 4; ++m)
#pragma unroll
    for (int r = 0; r < 4; ++r) {
      int row = wr * 64 + m * 16 + (lane >> 4) * 4 + r;
      f32x4 p0 = *(const f32x4*)&Red[row][0];
      f32x4 p1 = *(const f32x4*)&Red[row][4];
      float su = p0.x + p0.z + p1.x + p1.z;
      float sq = p0.y + p0.w + p1.y + p1.w;
      float mu = su * (1.f / 256.f);
      float var = fmaxf(sq * (1.f / 256.f) - mu * mu, 0.f);
      muv[m][r] = mu;
      rsv[m][r] = rsqrtf(var + 1e-5f);
    }

  if (MODE == 1) {  // proj_f: out = bf16(ln(vals))
#pragma unroll
    for (int m = 0; m < 4; ++m)
#pragma unroll
      for (int nf = 0; nf < 4; ++nf)
#pragma unroll
        for (int r = 0; r < 4; ++r) {
          int row = wr * 64 + m * 16 + (lane >> 4) * 4 + r;
          int col = wc * 64 + nf * 16 + (lane & 15);
          OutB[(size_t)(row0 + row) * 256 + col] =
              f2bf((acc[m][nf][r] + b1c[nf] - muv[m][r]) * rsv[m][r]);
        }
    return;
  }

  // g = gelu(res [+pf] + ln(vals)) -> bf16 in XOR-swizzled LDS (reuses Ash)
#pragma unroll
  for (int m = 0; m < 4; ++m)
#pragma unroll
    for (int nf = 0; nf < 4; ++nf)
#pragma unroll
      for (int r = 0; r < 4; ++r) {
        int row = wr * 64 + m * 16 + (lane >> 4) * 4 + r;
        int col = wc * 64 + nf * 16 + (lane & 15);
        float resv = Res[(size_t)(row0 + row) * 256 + col];
        if (MODE == 2) resv += bf2f(Pf[(size_t)(row0 + row) * 256 + col]);
        float gv = gelu_f(resv + (acc[m][nf][r] + b1c[nf] - muv[m][r]) * rsv[m][r]);
        int slot = (col >> 3) ^ (row & 7);
        *(unsigned short*)((char*)Gsh + row * 512 + slot * 16 + (col & 7) * 2) =
            f2bf(gv);
      }
  __syncthreads();

  // ---------------- GEMM2: K = 256 from Gsh ----------------
#pragma unroll
  for (int m = 0; m < 4; ++m)
#pragma unroll
    for (int nf = 0; nf < 4; ++nf) acc[m][nf] = (f32x4){0.f, 0.f, 0.f, 0.f};
#pragma unroll
  for (int k2 = 0; k2 < 4; ++k2) {
    const int ks = 2 * k2;
    LOADB_(bh1, bl1, W2h, W2l, ks + 1);
    MFMA2_(ks, bh0, bl0);
    if (ks + 2 < 8) LOADB_(bh0, bl0, W2h, W2l, ks + 2);
    MFMA2_(ks + 1, bh1, bl1);
  }

  // ---------------- Epilogue 2 ----------------
  float b2c[4];
#pragma unroll
  for (int nf = 0; nf < 4; ++nf) b2c[nf] = b2[wc * 64 + nf * 16 + (lane & 15)];
#pragma unroll
  for (int m = 0; m < 4; ++m)
#pragma unroll
    for (int r = 0; r < 4; ++r) {
      float su = 0.f, sq = 0.f;
#pragma unroll
      for (int nf = 0; nf < 4; ++nf) {
        float v = acc[m][nf][r] + b2c[nf];
        su += v; sq += v * v;
      }
#pragma unroll
      for (int off = 1; off < 16; off <<= 1) {
        su += __shfl_xor(su, off, 64);
        sq += __shfl_xor(sq, off, 64);
      }
      s1v[m][r] = su; s2v[m][r] = sq;
    }
  if ((lane & 15) == 0) {
#pragma unroll
    for (int m = 0; m < 4; ++m)
#pragma unroll
      for (int r = 0; r < 4; ++r) {
        int row = wr * 64 + m * 16 + (lane >> 4) * 4 + r;
        Red[row][2 * wc + 0] = s1v[m][r];
        Red[row][2 * wc + 1] = s2v[m][r];
      }
  }
  __syncthreads();
#pragma unroll
  for (int m = 0; m < 4; ++m)
#pragma unroll
    for (int r = 0; r < 4; ++r) {
      int row = wr * 64 + m * 16 + (lane >> 4) * 4 + r;
      f32x4 p0 = *(const f32x4*)&Red[row][0];
      f32x4 p1 = *(const f32x4*)&Red[row][4];
      float su = p0.x + p0.z + p1.x + p1.z;
      float sq = p0.y + p0.w + p1.y + p1.w;
      float mu = su * (1.f / 256.f);
      float var = fmaxf(sq * (1.f / 256.f) - mu * mu, 0.f);
      muv[m][r] = mu;
      rsv[m][r] = rsqrtf(var + 1e-5f);
    }
#pragma unroll
  for (int m = 0; m < 4; ++m)
#pragma unroll
    for (int nf = 0; nf < 4; ++nf)
#pragma unroll
      for (int r = 0; r < 4; ++r) {
        int row = wr * 64 + m * 16 + (lane >> 4) * 4 + r;
        int col = wc * 64 + nf * 16 + (lane & 15);
        float resv = Res[(size_t)(row0 + row) * 256 + col];
        OutF[(size_t)(row0 + row) * 256 + col] =
            gelu_f(resv + (acc[m][nf][r] + b2c[nf] - muv[m][r]) * rsv[m][r]);
      }
}

// ====== K6: Af[n,s,t,k] = sum_{v,c} q[t]*k[k]  (unnormalized) ============
__global__ __launch_bounds__(256) void temporal_A_kernel(
    const unsigned short* __restrict__ QK, float* __restrict__ A) {
  __shared__ __align__(16) float Qs[32 * 68];
  __shared__ __align__(16) float Ks[128 * 68];
  const int tt = blockIdx.x, s = blockIdx.y, n = blockIdx.z;
  const int tid = threadIdx.x;
  const int kg = tid & 15;   // k = kg + 16*j
  const int tp = tid >> 4;   // rows tp*2, tp*2+1
  float acc[2][8];
#pragma unroll
  for (int r = 0; r < 2; ++r)
#pragma unroll
    for (int j = 0; j < 8; ++j) acc[r][j] = 0.f;
  for (int v = 0; v < V_; ++v) {
    __syncthreads();
    for (int i = tid; i < 128 * 64; i += 256) {
      int k = i >> 6, c = i & 63;
      Ks[k * 68 + c] =
          bf2f(QK[(size_t)((n * T_ + k) * V_ + v) * J_ + c * 6 + 3 + s]);
    }
    for (int i = tid; i < 32 * 64; i += 256) {
      int t = i >> 6, c = i & 63;
      Qs[t * 68 + c] =
          bf2f(QK[(size_t)((n * T_ + tt * 32 + t) * V_ + v) * J_ + c * 6 + s]);
    }
    __syncthreads();
    for (int c = 0; c < 64; c += 4) {
      float4 q0 = *(const float4*)(Qs + (tp * 2 + 0) * 68 + c);
      float4 q1 = *(const float4*)(Qs + (tp * 2 + 1) * 68 + c);
#pragma unroll
      for (int j = 0; j < 8; ++j) {
        float4 kv = *(const float4*)(Ks + (kg + 16 * j) * 68 + c);
        acc[0][j] = fmaf(q0.x, kv.x, fmaf(q0.y, kv.y,
                    fmaf(q0.z, kv.z, fmaf(q0.w, kv.w, acc[0][j]))));
        acc[1][j] = fmaf(q1.x, kv.x, fmaf(q1.y, kv.y,
                    fmaf(q1.z, kv.z, fmaf(q1.w, kv.w, acc[1][j]))));
      }
    }
  }
  float* Ob = A + ((size_t)(n * S_ + s) * T_ + tt * 32) * T_;
#pragma unroll
  for (int r = 0; r < 2; ++r)
#pragma unroll
    for (int j = 0; j < 8; ++j)
      Ob[(tp * 2 + r) * T_ + kg + 16 * j] = acc[r][j];
}

// ====== K6b: mask (tril/triu) + row-normalize Af and Ab ==================
__global__ __launch_bounds__(64) void norm_temporal_kernel(
    float* __restrict__ Af, float* __restrict__ Ab) {
  const int row = blockIdx.x;  // (n*S+s)*T + t
  const int t = row & (T_ - 1);
  const int lane = threadIdx.x;
  float* A = blockIdx.y == 0 ? Af : Ab;
  const bool fw = blockIdx.y == 0;
  float v0 = A[(size_t)row * T_ + lane];
  float v1 = A[(size_t)row * T_ + lane + 64];
  v0 *= fw ? (lane <= t ? 1.f : 0.f) : (lane >= t ? 1.f : 0.f);
  v1 *= fw ? (lane + 64 <= t ? 1.f : 0.f) : (lane + 64 >= t ? 1.f : 0.f);
  float inv = 1.f / wave_sum(v0 + v1);
  A[(size_t)row * T_ + lane] = v0 * inv;
  A[(size_t)row * T_ + lane + 64] = v1 * inv;
}

// ====== K7: Z[n,s,t,vc] = bf16(sum_k A[n,s,t,k] * Y[n,k,vc]) — MFMA ======
__global__ __launch_bounds__(256, 3) void temporal_z_mfma_kernel(
    const float* __restrict__ A, const float* __restrict__ Y,
    unsigned short* __restrict__ Z) {
  __shared__ __align__(16) unsigned short Ahs[4 * 4 * 64 * 8];  // 16 KB
  __shared__ __align__(16) unsigned short Als[4 * 4 * 64 * 8];  // 16 KB
  __shared__ __align__(16) unsigned short Ys[16 * 64 * 8];      // 16 KB
  const int cb = blockIdx.x;                     // col block of 256
  const int s = blockIdx.y >> 1, rt = blockIdx.y & 1;
  const int n = blockIdx.z;
  const int tid = threadIdx.x, lane = tid & 63, w = tid >> 6;
  const int t0 = rt * 64;
  const float* Atile = A + ((size_t)(n * S_ + s) * T_ + t0) * T_;  // 64x128
  // convert A tile to frag-major bf16 hi/lo
  for (int i = tid; i < 64 * 128; i += 256) {
    int r = i >> 7, k = i & 127;
    float av = Atile[r * T_ + k];
    unsigned short h = f2bf(av);
    unsigned short l = f2bf(av - bf2f(h));
    int idx = ((((k >> 5) * 4 + (r >> 4)) * 64 + (r & 15) + 16 * ((k >> 3) & 3))
               << 3) | (k & 7);
    Ahs[idx] = h;
    Als[idx] = l;
  }
  f32x4 acc[4][4];
#pragma unroll
  for (int m = 0; m < 4; ++m)
#pragma unroll
    for (int nf = 0; nf < 4; ++nf) acc[m][nf] = (f32x4){0.f, 0.f, 0.f, 0.f};
  const float* Yb = Y + (size_t)n * (T_ * VC_) + cb * 256;
  for (int kstep = 0; kstep < 4; ++kstep) {
    __syncthreads();  // A-conversion done (iter 0) / prior Ys reads done
    for (int i = tid; i < 32 * 256; i += 256) {
      int kl = i >> 8, c = i & 255;
      float yv = Yb[(size_t)(kstep * 32 + kl) * VC_ + c];
      Ys[(((c >> 4) * 64 + (c & 15) + 16 * ((kl >> 3) & 3)) << 3) | (kl & 7)] =
          f2bf(yv);
    }
    __syncthreads();
    bf16x8 bv[4];
#pragma unroll
    for (int nf = 0; nf < 4; ++nf)
      bv[nf] = *(const bf16x8*)&Ys[((w * 4 + nf) * 64 + lane) * 8];
    bf16x8 af[4];
#pragma unroll
    for (int m = 0; m < 4; ++m)
      af[m] = *(const bf16x8*)&Ahs[((kstep * 4 + m) * 64 + lane) * 8];
#pragma unroll
    for (int nf = 0; nf < 4; ++nf)
#pragma unroll
      for (int m = 0; m < 4; ++m)
        acc[m][nf] = __builtin_amdgcn_mfma_f32_16x16x32_bf16(af[m], bv[nf], acc[m][nf], 0, 0, 0);
#pragma unroll
    for (int m = 0; m < 4; ++m)
      af[m] = *(const bf16x8*)&Als[((kstep * 4 + m) * 64 + lane) * 8];
#pragma unroll
    for (int nf = 0; nf < 4; ++nf)
#pragma unroll
      for (int m = 0; m < 4; ++m)
        acc[m][nf] = __builtin_amdgcn_mfma_f32_16x16x32_bf16(af[m], bv[nf], acc[m][nf], 0, 0, 0);
  }
  unsigned short* Zb = Z + ((size_t)(n * S_ + s) * T_ + t0) * VC_ + cb * 256;
#pragma unroll
  for (int m = 0; m < 4; ++m)
#pragma unroll
    for (int nf = 0; nf < 4; ++nf)
#pragma unroll
      for (int r = 0; r < 4; ++r) {
        int trow = m * 16 + (lane >> 4) * 4 + r;
        int col = w * 64 + nf * 16 + (lane & 15);
        Zb[(size_t)trow * VC_ + col] = f2bf(acc[m][nf][r]);
      }
}

extern "C" void kernel_launch(void* const* d_in, const int* in_sizes, int n_in,
                              void* d_out, int out_size, void* d_ws,
                              size_t ws_size, hipStream_t stream) {
  const float* x      = (const float*)d_in[0];
  const float* W_ins  = (const float*)d_in[1];
  const float* b_ins  = (const float*)d_in[2];
  const float* att0   = (const float*)d_in[3];
  const float* W_outs = (const float*)d_in[4];
  const float* b_outs = (const float*)d_in[5];
  const float* W_ffs  = (const float*)d_in[6];
  const float* b_ffs  = (const float*)d_in[7];
  const float* W_inf  = (const float*)d_in[8];
  const float* b_inf  = (const float*)d_in[9];
  const float* W_inb  = (const float*)d_in[10];
  const float* b_inb  = (const float*)d_in[11];
  const float* W_outf = (const float*)d_in[12];
  const float* b_outf = (const float*)d_in[13];
  const float* W_outb = (const float*)d_in[14];
  const float* b_outb = (const float*)d_in[15];
  const float* W_fft  = (const float*)d_in[16];
  const float* b_fft  = (const float*)d_in[17];
  float* out = (float*)d_out;
  char* base = (char*)d_ws;

  // Workspace layout (bytes). Peak = 657,675,008 B ≈ 627.2 MiB.
  unsigned short* B0    = (unsigned short*)base;
  float*          y2    = (float*)(base + 314572800);           // 209.7 MB fp32
  unsigned short* projf = (unsigned short*)(base + 524288000);  // 104.9 MB bf16
  float*          Asp   = (float*)(base + 629145600);           // 0.48 MB
  float*          Af    = (float*)(base + 629625600);           // 12.6 MB
  float*          Ab    = (float*)(base + 642208512);           // 12.6 MB
  unsigned short* Wouts_h = (unsigned short*)(base + 654791424);
  unsigned short* Wouts_l = (unsigned short*)(base + 655184640);
  unsigned short* Wffs_h  = (unsigned short*)(base + 655577856);
  unsigned short* Wffs_l  = (unsigned short*)(base + 655708928);
  unsigned short* Woutf_h = (unsigned short*)(base + 655840000);
  unsigned short* Woutf_l = (unsigned short*)(base + 656233216);
  unsigned short* Woutb_h = (unsigned short*)(base + 656626432);
  unsigned short* Woutb_l = (unsigned short*)(base + 657019648);
  unsigned short* Wfft_h  = (unsigned short*)(base + 657412864);
  unsigned short* Wfft_l  = (unsigned short*)(base + 657543936);

  unsigned short* QKs  = B0;
  unsigned short* Y768 = B0;
  unsigned short* QKf  = B0;
  unsigned short* QKb  = B0 + 78643200;
  unsigned short* Zbuf = B0;

  // ---- weight prep (fragment-major bf16 hi/lo) ----
  prep_w_kernel<<<768, 256, 0, stream>>>(W_outs, 3, Wouts_h, Wouts_l);
  prep_w_kernel<<<256, 256, 0, stream>>>(W_ffs, 1, Wffs_h, Wffs_l);
  prep_w_kernel<<<768, 256, 0, stream>>>(W_outf, 3, Woutf_h, Woutf_l);
  prep_w_kernel<<<768, 256, 0, stream>>>(W_outb, 3, Woutb_h, Woutb_l);
  prep_w_kernel<<<256, 256, 0, stream>>>(W_fft, 1, Wfft_h, Wfft_l);

  // ---- spatial stage ----
  gemm_in_kernel<<<NT_, 128, 0, stream>>>(x, W_ins, b_ins, QKs);
  hipMemsetAsync(Asp, 0, (size_t)N_ * S_ * V_ * V_ * sizeof(float), stream);
  spatial_A_kernel<<<N_ * 8, 256, 0, stream>>>(QKs, Asp);
  norm_A_kernel<<<N_ * S_ * V_, 64, 0, stream>>>(Asp, att0);
  y768_kernel<<<NT_ / 2, 256, 0, stream>>>(x, Asp, Y768);
  mfma_proj_kernel<0><<<1600, 512, 0, stream>>>(
      Y768, Wouts_h, Wouts_l, b_outs, x, nullptr, Wffs_h, Wffs_l, b_ffs, y2,
      nullptr);
  // ---- temporal stage ----
  gemm_in_kernel<<<NT_, 128, 0, stream>>>(y2, W_inf, b_inf, QKf);
  gemm_in_kernel<<<NT_, 128, 0, stream>>>(y2, W_inb, b_inb, QKb);
  temporal_A_kernel<<<dim3(4, 3, 64), 256, 0, stream>>>(QKf, Af);
  temporal_A_kernel<<<dim3(4, 3, 64), 256, 0, stream>>>(QKb, Ab);
  norm_temporal_kernel<<<dim3(N_ * S_ * T_, 2), 64, 0, stream>>>(Af, Ab);
  // forward: Zf -> projf (Zbuf overlays dead QKf/QKb)
  temporal_z_mfma_kernel<<<dim3(25, 6, 64), 256, 0, stream>>>(Af, y2, Zbuf);
  mfma_proj_kernel<1><<<1600, 512, 0, stream>>>(
      Zbuf, Woutf_h, Woutf_l, b_outf, nullptr, nullptr, nullptr, nullptr,
      nullptr, nullptr, projf);
  // backward: Zb -> fused projection + final output
  temporal_z_mfma_kernel<<<dim3(25, 6, 64), 256, 0, stream>>>(Ab, y2, Zbuf);
  mfma_proj_kernel<2><<<1600, 512, 0, stream>>>(
      Zbuf, Woutb_h, Woutb_l, b_outb, y2, projf, Wfft_h, Wfft_l, b_fft, out,
      nullptr);
}

// Round 6
// 5485.024 us; speedup vs baseline: 1.2255x; 1.0107x over previous
//
#include <hip/hip_runtime.h>
#include <math.h>

// Problem constants (N,T,V,C,S,CI) = (64,128,25,256,3,64)
constexpr int N_ = 64, T_ = 128, V_ = 25, C_ = 256, S_ = 3;
constexpr int J_ = 384;          // 2*S*CI
constexpr int NT_ = N_ * T_;     // 8192
constexpr int VC_ = V_ * C_;     // 6400
constexpr int SC_ = S_ * C_;     // 768

__device__ __forceinline__ float gelu_f(float x) {
  return 0.5f * x * (1.0f + erff(x * 0.70710678118654752440f));
}
__device__ __forceinline__ float elup1(float x) {  // elu(x)+1
  return x > 0.0f ? x + 1.0f : __expf(x);
}
__device__ __forceinline__ float wave_sum(float x) {
#pragma unroll
  for (int off = 1; off < 64; off <<= 1) x += __shfl_xor(x, off, 64);
  return x;
}
// bf16 storage helpers (storage-only; all math fp32)
__device__ __forceinline__ float bf2f(unsigned short u) {
  union { unsigned int i; float f; } v; v.i = ((unsigned int)u) << 16;
  return v.f;
}
__device__ __forceinline__ unsigned short f2bf(float f) {
  union { float f; unsigned int i; } v; v.f = f;
  unsigned int r = v.i + 0x7fffu + ((v.i >> 16) & 1u);  // RNE
  return (unsigned short)(r >> 16);
}

// MFMA fragment types (verified layout: A row=lane&15, a[j] k=(lane>>4)*8+j;
// B col=lane&15, b[j] same k; C/D col=lane&15, row=(lane>>4)*4+reg)
typedef short bf16x8 __attribute__((ext_vector_type(8)));
typedef float f32x4 __attribute__((ext_vector_type(4)));

// ================= K1: out = bf16(elu(X @ W + b) + 1) ====================
__global__ __launch_bounds__(128) void gemm_in_kernel(
    const float* __restrict__ X, const float* __restrict__ W,
    const float* __restrict__ b, unsigned short* __restrict__ out) {
  __shared__ __align__(16) float xs[VC_];
  const int blk = blockIdx.x;
  const int tid = threadIdx.x;
  const float* Xb = X + (size_t)blk * VC_;
  for (int i = tid; i < VC_; i += 128) xs[i] = Xb[i];
  __syncthreads();
  const int lane = tid & 63, wave = tid >> 6;
  const int nr = wave == 0 ? 13 : 12;
  float acc[13][6];
#pragma unroll
  for (int r = 0; r < 13; ++r)
#pragma unroll
    for (int q = 0; q < 6; ++q) acc[r][q] = 0.f;
#pragma unroll 2
  for (int c = 0; c < C_; ++c) {
    float w[6];
#pragma unroll
    for (int q = 0; q < 6; ++q) w[q] = W[c * J_ + lane + 64 * q];
#pragma unroll
    for (int r = 0; r < 13; ++r) {
      int v = wave + 2 * r;
      float xv = xs[(v < V_ ? v : V_ - 1) * C_ + c];
#pragma unroll
      for (int q = 0; q < 6; ++q) acc[r][q] = fmaf(xv, w[q], acc[r][q]);
    }
  }
  float bj[6];
#pragma unroll
  for (int q = 0; q < 6; ++q) bj[q] = b[lane + 64 * q];
  unsigned short* Ob = out + (size_t)blk * (V_ * J_);
#pragma unroll
  for (int r = 0; r < 13; ++r) {
    int v = wave + 2 * r;
    if (r < nr) {
#pragma unroll
      for (int q = 0; q < 6; ++q)
        Ob[v * J_ + lane + 64 * q] = f2bf(elup1(acc[r][q] + bj[q]));
    }
  }
}

// ============ K2: spatial gram A[n,s,v,u] += sum_{t,c} q*k ===============
// LDS row stride padded 384 -> 390 (mod 32 = 6): k-operand reads across
// pu=0..24 hit >=16 distinct banks (worst 2-way, free).
constexpr int PJ_ = 390;  // padded LDS row stride (floats)
__global__ __launch_bounds__(256) void spatial_A_kernel(
    const unsigned short* __restrict__ QK, float* __restrict__ A) {
  __shared__ __align__(16) float qk[V_ * PJ_];  // 39.0 KB
  const int n = blockIdx.x >> 3, tq = blockIdx.x & 7;
  const int tid = threadIdx.x;
  float acc[3][3];
#pragma unroll
  for (int i = 0; i < 3; ++i)
#pragma unroll
    for (int s = 0; s < 3; ++s) acc[i][s] = 0.f;
  int pv[3], pu[3];
#pragma unroll
  for (int i = 0; i < 3; ++i) {
    int p = tid + 256 * i;
    pv[i] = p / V_;
    pu[i] = p - V_ * pv[i];
  }
  for (int tt = 0; tt < 16; ++tt) {
    int t = tq * 16 + tt;
    const ushort4* src4 =
        (const ushort4*)(QK + (size_t)(n * T_ + t) * (V_ * J_));
    __syncthreads();
    for (int i = tid; i < V_ * J_ / 4; i += 256) {
      int row = i / 96, wi = i - row * 96;  // 96 = J_/4
      ushort4 u = src4[i];
      float* d = qk + row * PJ_ + wi * 4;
      d[0] = bf2f(u.x);
      d[1] = bf2f(u.y);
      d[2] = bf2f(u.z);
      d[3] = bf2f(u.w);
    }
    __syncthreads();
#pragma unroll
    for (int i = 0; i < 3; ++i) {
      if (tid + 256 * i < 625) {
        const float* qr = qk + pv[i] * PJ_;
        const float* kr = qk + pu[i] * PJ_;
        for (int c = 0; c < 64; ++c) {
          float2 q01 = *(const float2*)(qr + c * 6);
          float q2 = qr[c * 6 + 2];
          float k0 = kr[c * 6 + 3];
          float2 k12 = *(const float2*)(kr + c * 6 + 4);
          acc[i][0] = fmaf(q01.x, k0, acc[i][0]);
          acc[i][1] = fmaf(q01.y, k12.x, acc[i][1]);
          acc[i][2] = fmaf(q2, k12.y, acc[i][2]);
        }
      }
    }
  }
#pragma unroll
  for (int i = 0; i < 3; ++i)
    if (tid + 256 * i < 625) {
#pragma unroll
      for (int s = 0; s < 3; ++s)
        atomicAdd(&A[((n * S_ + s) * V_ + pv[i]) * V_ + pu[i]], acc[i][s]);
    }
}

// ======= K3: A = A / rowsum + att0 ========================================
__global__ __launch_bounds__(64) void norm_A_kernel(
    float* __restrict__ A, const float* __restrict__ att0) {
  const int row = blockIdx.x;           // (n*S+s)*V + v
  const int sv = row % (S_ * V_);       // s*V + v
  const int lane = threadIdx.x;
  float val = (lane < V_) ? A[row * V_ + lane] : 0.f;
  float sum = wave_sum(val);
  if (lane < V_) A[row * V_ + lane] = val / sum + att0[sv * V_ + lane];
}

// ====== K4a: y768[nt, v, s, c] = bf16(sum_u A[n,s,v,u] * x[nt,u,c]) ======
__global__ __launch_bounds__(256) void y768_kernel(
    const float* __restrict__ X, const float* __restrict__ A,
    unsigned short* __restrict__ Y768) {
  __shared__ __align__(16) float xs[2 * VC_];      // 51.2 KB
  __shared__ __align__(16) float As[S_ * V_ * 28]; // padded rows
  const int nt0 = blockIdx.x * 2;
  const int n = nt0 >> 7;
  const int tid = threadIdx.x;  // = c
  for (int i = tid; i < 2 * VC_; i += 256)
    xs[i] = X[(size_t)nt0 * VC_ + i];
  const float* Abase = A + n * (S_ * V_ * V_);
  for (int i = tid; i < S_ * V_ * V_; i += 256) {
    int r = i / V_, u = i - r * V_;
    As[r * 28 + u] = Abase[i];
  }
  __syncthreads();
  float xu0[V_], xu1[V_];
#pragma unroll
  for (int u = 0; u < V_; ++u) {
    xu0[u] = xs[u * C_ + tid];
    xu1[u] = xs[VC_ + u * C_ + tid];
  }
  unsigned short* Ob0 = Y768 + (size_t)nt0 * (V_ * SC_);
  unsigned short* Ob1 = Ob0 + (V_ * SC_);
  for (int v = 0; v < V_; ++v) {
#pragma unroll
    for (int s = 0; s < 3; ++s) {
      const float* Ar = As + (s * V_ + v) * 28;
      float a0 = 0.f, a1 = 0.f;
#pragma unroll
      for (int u = 0; u < V_; ++u) {
        float av = Ar[u];
        a0 = fmaf(av, xu0[u], a0);
        a1 = fmaf(av, xu1[u], a1);
      }
      Ob0[(v * S_ + s) * C_ + tid] = f2bf(a0);
      Ob1[(v * S_ + s) * C_ + tid] = f2bf(a1);
    }
  }
}

// ====== K5: weight prep — fragment-major bf16 hi/lo =====================
__global__ __launch_bounds__(256) void prep_w_kernel(
    const float* __restrict__ W, int nS, unsigned short* __restrict__ hi,
    unsigned short* __restrict__ lo) {
  int idx = blockIdx.x * 256 + threadIdx.x;
  int j = idx & 7, l = (idx >> 3) & 63, nfg = (idx >> 9) & 15,
      kstep = (idx >> 13) & 7, s = idx >> 16;
  int col = nfg * 16 + (l & 15);
  int k = kstep * 32 + (l >> 4) * 8 + j;
  float v = W[(k * nS + s) * 256 + col];
  unsigned short h = f2bf(v);
  hi[idx] = h;
  lo[idx] = f2bf(v - bf2f(h));
}

// ====== MFMA projection kernel (8 waves / 512 threads) ===================
// MODE 0: spatial_out  g=gelu(X+ln(Y768@Wo+bo)); out=gelu(X+ln(g@Wf+bf)) f32
// MODE 1: proj_f       out = bf16(ln(Z@Wo+bo))
// MODE 2: proj_final_b g=gelu(Y+Pf+ln(Z@Wo+bo)); out=gelu(Y+ln(g@Wt+bt)) f32
// r6: 128x256 tile kept (32 MFMAs per B-load set), but ALL cross-phase
// register prefetches removed: single B buffer (32 regs), load-ahead-by-one
// only WITHIN a phase. Peak live ~110 regs -> fits the 128-VGPR tier the
// allocator insists on (r5's dbuf demanded ~190 -> 400 MB scratch stores).
// Phase-start latencies (4 x ~200cyc/block) are hidden by the co-resident
// block (LDS 68 KB -> 2 blocks/CU; <=128 VGPR -> 4 waves/SIMD).
#define LOADB_(dh, dl, Wh, Wl, sk)                                         \
  {                                                                        \
    _Pragma("unroll") for (int nf_ = 0; nf_ < 4; ++nf_) {                  \
      int wo_ = ((sk) * 16 + (wc * 4 + nf_)) * 512 + lane * 8;             \
      dh[nf_] = *(const bf16x8*)((Wh) + wo_);                              \
      dl[nf_] = *(const bf16x8*)((Wl) + wo_);                              \
    }                                                                      \
  }

#define MFMA1_(ks, BH, BL)                                                 \
  {                                                                        \
    _Pragma("unroll") for (int m_ = 0; m_ < 4; ++m_) {                     \
      bf16x8 af_ = *(const bf16x8*)&Ash[(((ks) * 8 + (wr * 4 + m_)) * 64 + \
                                         lane) * 8];                       \
      _Pragma("unroll") for (int nf_ = 0; nf_ < 4; ++nf_) {                \
        acc[m_][nf_] = __builtin_amdgcn_mfma_f32_16x16x32_bf16(            \
            af_, BH[nf_], acc[m_][nf_], 0, 0, 0);                          \
        acc[m_][nf_] = __builtin_amdgcn_mfma_f32_16x16x32_bf16(            \
            af_, BL[nf_], acc[m_][nf_], 0, 0, 0);                          \
      }                                                                    \
    }                                                                      \
  }

#define MFMA2_(ks, BH, BL)                                                 \
  {                                                                        \
    _Pragma("unroll") for (int m_ = 0; m_ < 4; ++m_) {                     \
      int row_ = wr * 64 + m_ * 16 + (lane & 15);                          \
      int slot_ = ((ks) * 4 + (lane >> 4)) ^ (row_ & 7);                   \
      bf16x8 af_ =                                                         \
          *(const bf16x8*)((const char*)Gsh + row_ * 512 + slot_ * 16);    \
      _Pragma("unroll") for (int nf_ = 0; nf_ < 4; ++nf_) {                \
        acc[m_][nf_] = __builtin_amdgcn_mfma_f32_16x16x32_bf16(            \
            af_, BH[nf_], acc[m_][nf_], 0, 0, 0);                          \
        acc[m_][nf_] = __builtin_amdgcn_mfma_f32_16x16x32_bf16(            \
            af_, BL[nf_], acc[m_][nf_], 0, 0, 0);                          \
      }                                                                    \
    }                                                                      \
  }

template <int MODE>
__global__ __launch_bounds__(512, 2) void mfma_proj_kernel(
    const unsigned short* __restrict__ A,    // bf16 GEMM1 input
    const unsigned short* __restrict__ W1h, const unsigned short* __restrict__ W1l,
    const float* __restrict__ b1,
    const float* __restrict__ Res,           // fp32 residual (X or y2)
    const unsigned short* __restrict__ Pf,   // bf16 (MODE 2)
    const unsigned short* __restrict__ W2h, const unsigned short* __restrict__ W2l,
    const float* __restrict__ b2,
    float* __restrict__ OutF,                // MODE 0/2
    unsigned short* __restrict__ OutB) {     // MODE 1
  __shared__ __align__(16) unsigned short Ash[8 * 8 * 64 * 8];  // 64 KB; reused as G
  __shared__ __align__(16) float Red[128][8];                   // 4 KB LN partials
  unsigned short* Gsh = Ash;
  const int tid = threadIdx.x, lane = tid & 63, w = tid >> 6;
  const int wr = w >> 2, wc = w & 3;
  const int bid = blockIdx.x;
  const int n = bid / 25, mt = bid - n * 25;
  const int row0 = n * 3200 + mt * 128;  // flat row (nt*25+v) for Res/Pf/Out
  size_t abase, asstride;
  int arstride;
  if (MODE == 0) {  // Y768: [flat_row][s*256 + c], row stride 768
    abase = (size_t)row0 * 768; arstride = 768; asstride = 256;
  } else {          // Z: [n][s][flat_tv][c]
    abase = (size_t)n * ((size_t)S_ * T_ * VC_) + (size_t)(mt * 128) * 256;
    arstride = 256; asstride = (size_t)T_ * VC_;
  }

  f32x4 acc[4][4];
#pragma unroll
  for (int m = 0; m < 4; ++m)
#pragma unroll
    for (int nf = 0; nf < 4; ++nf) acc[m][nf] = (f32x4){0.f, 0.f, 0.f, 0.f};

  bf16x8 bh[4], bl[4];

  // ---------------- GEMM1: K = 768 (3 s-slabs of 256) ----------------
  for (int s = 0; s < 3; ++s) {
    int4 streg[8];
#pragma unroll
    for (int i = 0; i < 8; ++i) {
      int ck = w * 8 + i, ks = ck >> 3, mg = ck & 7;
      int row = mg * 16 + (lane & 15);
      int koff = ks * 32 + (lane >> 4) * 8;
      streg[i] = *(const int4*)(A + abase + (size_t)s * asstride +
                                (size_t)row * arstride + koff);
    }
    __syncthreads();  // readers of previous slab done
#pragma unroll
    for (int i = 0; i < 8; ++i)
      *(int4*)&Ash[((w * 8 + i) * 64 + lane) * 8] = streg[i];
    __syncthreads();
    LOADB_(bh, bl, W1h, W1l, s * 8);
#pragma unroll 2
    for (int ks = 0; ks < 8; ++ks) {
      MFMA1_(ks, bh, bl);
      if (ks < 7) LOADB_(bh, bl, W1h, W1l, s * 8 + ks + 1);
    }
  }

  // ---------------- Epilogue 1: per-row LayerNorm stats ----------------
  float b1c[4];
#pragma unroll
  for (int nf = 0; nf < 4; ++nf) b1c[nf] = b1[wc * 64 + nf * 16 + (lane & 15)];
  float s1v[4][4], s2v[4][4];
#pragma unroll
  for (int m = 0; m < 4; ++m)
#pragma unroll
    for (int r = 0; r < 4; ++r) {
      float su = 0.f, sq = 0.f;
#pragma unroll
      for (int nf = 0; nf < 4; ++nf) {
        float v = acc[m][nf][r] + b1c[nf];
        su += v; sq += v * v;
      }
#pragma unroll
      for (int off = 1; off < 16; off <<= 1) {
        su += __shfl_xor(su, off, 64);
        sq += __shfl_xor(sq, off, 64);
      }
      s1v[m][r] = su; s2v[m][r] = sq;
    }
  if ((lane & 15) == 0) {
#pragma unroll
    for (int m = 0; m < 4; ++m)
#pragma unroll
      for (int r = 0; r < 4; ++r) {
        int row = wr * 64 + m * 16 + (lane >> 4) * 4 + r;
        Red[row][2 * wc + 0] = s1v[m][r];
        Red[row][2 * wc + 1] = s2v[m][r];
      }
  }
  __syncthreads();
  float muv[4][4], rsv[4][4];
#pragma unroll
  for (int m = 0; m < 4; ++m)
#pragma unroll
    for (int r = 0; r < 4; ++r) {
      int row = wr * 64 + m * 16 + (lane >> 4) * 4 + r;
      f32x4 p0 = *(const f32x4*)&Red[row][0];
      f32x4 p1 = *(const f32x4*)&Red[row][4];
      float su = p0.x + p0.z + p1.x + p1.z;
      float sq = p0.y + p0.w + p1.y + p1.w;
      float mu = su * (1.f / 256.f);
      float var = fmaxf(sq * (1.f / 256.f) - mu * mu, 0.f);
      muv[m][r] = mu;
      rsv[m][r] = rsqrtf(var + 1e-5f);
    }

  if (MODE == 1) {  // proj_f: out = bf16(ln(vals))
#pragma unroll
    for (int m = 0; m < 4; ++m)
#pragma unroll
      for (int nf = 0; nf < 4; ++nf)
#pragma unroll
        for (int r = 0; r < 4; ++r) {
          int row = wr * 64 + m * 16 + (lane >> 4) * 4 + r;
          int col = wc * 64 + nf * 16 + (lane & 15);
          OutB[(size_t)(row0 + row) * 256 + col] =
              f2bf((acc[m][nf][r] + b1c[nf] - muv[m][r]) * rsv[m][r]);
        }
    return;
  }

  // g = gelu(res [+pf] + ln(vals)) -> bf16 in XOR-swizzled LDS (reuses Ash)
#pragma unroll
  for (int m = 0; m < 4; ++m)
#pragma unroll
    for (int nf = 0; nf < 4; ++nf)
#pragma unroll
      for (int r = 0; r < 4; ++r) {
        int row = wr * 64 + m * 16 + (lane >> 4) * 4 + r;
        int col = wc * 64 + nf * 16 + (lane & 15);
        float resv = Res[(size_t)(row0 + row) * 256 + col];
        if (MODE == 2) resv += bf2f(Pf[(size_t)(row0 + row) * 256 + col]);
        float gv = gelu_f(resv + (acc[m][nf][r] + b1c[nf] - muv[m][r]) * rsv[m][r]);
        int slot = (col >> 3) ^ (row & 7);
        *(unsigned short*)((char*)Gsh + row * 512 + slot * 16 + (col & 7) * 2) =
            f2bf(gv);
      }
  __syncthreads();

  // ---------------- GEMM2: K = 256 from Gsh ----------------
#pragma unroll
  for (int m = 0; m < 4; ++m)
#pragma unroll
    for (int nf = 0; nf < 4; ++nf) acc[m][nf] = (f32x4){0.f, 0.f, 0.f, 0.f};
  LOADB_(bh, bl, W2h, W2l, 0);
#pragma unroll 2
  for (int ks = 0; ks < 8; ++ks) {
    MFMA2_(ks, bh, bl);
    if (ks < 7) LOADB_(bh, bl, W2h, W2l, ks + 1);
  }

  // ---------------- Epilogue 2 ----------------
  float b2c[4];
#pragma unroll
  for (int nf = 0; nf < 4; ++nf) b2c[nf] = b2[wc * 64 + nf * 16 + (lane & 15)];
#pragma unroll
  for (int m = 0; m < 4; ++m)
#pragma unroll
    for (int r = 0; r < 4; ++r) {
      float su = 0.f, sq = 0.f;
#pragma unroll
      for (int nf = 0; nf < 4; ++nf) {
        float v = acc[m][nf][r] + b2c[nf];
        su += v; sq += v * v;
      }
#pragma unroll
      for (int off = 1; off < 16; off <<= 1) {
        su += __shfl_xor(su, off, 64);
        sq += __shfl_xor(sq, off, 64);
      }
      s1v[m][r] = su; s2v[m][r] = sq;
    }
  if ((lane & 15) == 0) {
#pragma unroll
    for (int m = 0; m < 4; ++m)
#pragma unroll
      for (int r = 0; r < 4; ++r) {
        int row = wr * 64 + m * 16 + (lane >> 4) * 4 + r;
        Red[row][2 * wc + 0] = s1v[m][r];
        Red[row][2 * wc + 1] = s2v[m][r];
      }
  }
  __syncthreads();
#pragma unroll
  for (int m = 0; m < 4; ++m)
#pragma unroll
    for (int r = 0; r < 4; ++r) {
      int row = wr * 64 + m * 16 + (lane >> 4) * 4 + r;
      f32x4 p0 = *(const f32x4*)&Red[row][0];
      f32x4 p1 = *(const f32x4*)&Red[row][4];
      float su = p0.x + p0.z + p1.x + p1.z;
      float sq = p0.y + p0.w + p1.y + p1.w;
      float mu = su * (1.f / 256.f);
      float var = fmaxf(sq * (1.f / 256.f) - mu * mu, 0.f);
      muv[m][r] = mu;
      rsv[m][r] = rsqrtf(var + 1e-5f);
    }
#pragma unroll
  for (int m = 0; m < 4; ++m)
#pragma unroll
    for (int nf = 0; nf < 4; ++nf)
#pragma unroll
      for (int r = 0; r < 4; ++r) {
        int row = wr * 64 + m * 16 + (lane >> 4) * 4 + r;
        int col = wc * 64 + nf * 16 + (lane & 15);
        float resv = Res[(size_t)(row0 + row) * 256 + col];
        OutF[(size_t)(row0 + row) * 256 + col] =
            gelu_f(resv + (acc[m][nf][r] + b2c[nf] - muv[m][r]) * rsv[m][r]);
      }
}

// ====== K6: Af[n,s,t,k] = sum_{v,c} q[t]*k[k]  (unnormalized) ============
__global__ __launch_bounds__(256) void temporal_A_kernel(
    const unsigned short* __restrict__ QK, float* __restrict__ A) {
  __shared__ __align__(16) float Qs[32 * 68];
  __shared__ __align__(16) float Ks[128 * 68];
  const int tt = blockIdx.x, s = blockIdx.y, n = blockIdx.z;
  const int tid = threadIdx.x;
  const int kg = tid & 15;   // k = kg + 16*j
  const int tp = tid >> 4;   // rows tp*2, tp*2+1
  float acc[2][8];
#pragma unroll
  for (int r = 0; r < 2; ++r)
#pragma unroll
    for (int j = 0; j < 8; ++j) acc[r][j] = 0.f;
  for (int v = 0; v < V_; ++v) {
    __syncthreads();
    for (int i = tid; i < 128 * 64; i += 256) {
      int k = i >> 6, c = i & 63;
      Ks[k * 68 + c] =
          bf2f(QK[(size_t)((n * T_ + k) * V_ + v) * J_ + c * 6 + 3 + s]);
    }
    for (int i = tid; i < 32 * 64; i += 256) {
      int t = i >> 6, c = i & 63;
      Qs[t * 68 + c] =
          bf2f(QK[(size_t)((n * T_ + tt * 32 + t) * V_ + v) * J_ + c * 6 + s]);
    }
    __syncthreads();
    for (int c = 0; c < 64; c += 4) {
      float4 q0 = *(const float4*)(Qs + (tp * 2 + 0) * 68 + c);
      float4 q1 = *(const float4*)(Qs + (tp * 2 + 1) * 68 + c);
#pragma unroll
      for (int j = 0; j < 8; ++j) {
        float4 kv = *(const float4*)(Ks + (kg + 16 * j) * 68 + c);
        acc[0][j] = fmaf(q0.x, kv.x, fmaf(q0.y, kv.y,
                    fmaf(q0.z, kv.z, fmaf(q0.w, kv.w, acc[0][j]))));
        acc[1][j] = fmaf(q1.x, kv.x, fmaf(q1.y, kv.y,
                    fmaf(q1.z, kv.z, fmaf(q1.w, kv.w, acc[1][j]))));
      }
    }
  }
  float* Ob = A + ((size_t)(n * S_ + s) * T_ + tt * 32) * T_;
#pragma unroll
  for (int r = 0; r < 2; ++r)
#pragma unroll
    for (int j = 0; j < 8; ++j)
      Ob[(tp * 2 + r) * T_ + kg + 16 * j] = acc[r][j];
}

// ====== K6b: mask (tril/triu) + row-normalize Af and Ab ==================
__global__ __launch_bounds__(64) void norm_temporal_kernel(
    float* __restrict__ Af, float* __restrict__ Ab) {
  const int row = blockIdx.x;  // (n*S+s)*T + t
  const int t = row & (T_ - 1);
  const int lane = threadIdx.x;
  float* A = blockIdx.y == 0 ? Af : Ab;
  const bool fw = blockIdx.y == 0;
  float v0 = A[(size_t)row * T_ + lane];
  float v1 = A[(size_t)row * T_ + lane + 64];
  v0 *= fw ? (lane <= t ? 1.f : 0.f) : (lane >= t ? 1.f : 0.f);
  v1 *= fw ? (lane + 64 <= t ? 1.f : 0.f) : (lane + 64 >= t ? 1.f : 0.f);
  float inv = 1.f / wave_sum(v0 + v1);
  A[(size_t)row * T_ + lane] = v0 * inv;
  A[(size_t)row * T_ + lane + 64] = v1 * inv;
}

// ====== K7: Z[n,s,t,vc] = bf16(sum_k A[n,s,t,k] * Y[n,k,vc]) — MFMA ======
__global__ __launch_bounds__(256, 3) void temporal_z_mfma_kernel(
    const float* __restrict__ A, const float* __restrict__ Y,
    unsigned short* __restrict__ Z) {
  __shared__ __align__(16) unsigned short Ahs[4 * 4 * 64 * 8];  // 16 KB
  __shared__ __align__(16) unsigned short Als[4 * 4 * 64 * 8];  // 16 KB
  __shared__ __align__(16) unsigned short Ys[16 * 64 * 8];      // 16 KB
  const int cb = blockIdx.x;                     // col block of 256
  const int s = blockIdx.y >> 1, rt = blockIdx.y & 1;
  const int n = blockIdx.z;
  const int tid = threadIdx.x, lane = tid & 63, w = tid >> 6;
  const int t0 = rt * 64;
  const float* Atile = A + ((size_t)(n * S_ + s) * T_ + t0) * T_;  // 64x128
  // convert A tile to frag-major bf16 hi/lo
  for (int i = tid; i < 64 * 128; i += 256) {
    int r = i >> 7, k = i & 127;
    float av = Atile[r * T_ + k];
    unsigned short h = f2bf(av);
    unsigned short l = f2bf(av - bf2f(h));
    int idx = ((((k >> 5) * 4 + (r >> 4)) * 64 + (r & 15) + 16 * ((k >> 3) & 3))
               << 3) | (k & 7);
    Ahs[idx] = h;
    Als[idx] = l;
  }
  f32x4 acc[4][4];
#pragma unroll
  for (int m = 0; m < 4; ++m)
#pragma unroll
    for (int nf = 0; nf < 4; ++nf) acc[m][nf] = (f32x4){0.f, 0.f, 0.f, 0.f};
  const float* Yb = Y + (size_t)n * (T_ * VC_) + cb * 256;
  for (int kstep = 0; kstep < 4; ++kstep) {
    __syncthreads();  // A-conversion done (iter 0) / prior Ys reads done
    for (int i = tid; i < 32 * 256; i += 256) {
      int kl = i >> 8, c = i & 255;
      float yv = Yb[(size_t)(kstep * 32 + kl) * VC_ + c];
      Ys[(((c >> 4) * 64 + (c & 15) + 16 * ((kl >> 3) & 3)) << 3) | (kl & 7)] =
          f2bf(yv);
    }
    __syncthreads();
    bf16x8 bv[4];
#pragma unroll
    for (int nf = 0; nf < 4; ++nf)
      bv[nf] = *(const bf16x8*)&Ys[((w * 4 + nf) * 64 + lane) * 8];
    bf16x8 af[4];
#pragma unroll
    for (int m = 0; m < 4; ++m)
      af[m] = *(const bf16x8*)&Ahs[((kstep * 4 + m) * 64 + lane) * 8];
#pragma unroll
    for (int nf = 0; nf < 4; ++nf)
#pragma unroll
      for (int m = 0; m < 4; ++m)
        acc[m][nf] = __builtin_amdgcn_mfma_f32_16x16x32_bf16(af[m], bv[nf], acc[m][nf], 0, 0, 0);
#pragma unroll
    for (int m = 0; m < 4; ++m)
      af[m] = *(const bf16x8*)&Als[((kstep * 4 + m) * 64 + lane) * 8];
#pragma unroll
    for (int nf = 0; nf < 4; ++nf)
#pragma unroll
      for (int m = 0; m < 4; ++m)
        acc[m][nf] = __builtin_amdgcn_mfma_f32_16x16x32_bf16(af[m], bv[nf], acc[m][nf], 0, 0, 0);
  }
  unsigned short* Zb = Z + ((size_t)(n * S_ + s) * T_ + t0) * VC_ + cb * 256;
#pragma unroll
  for (int m = 0; m < 4; ++m)
#pragma unroll
    for (int nf = 0; nf < 4; ++nf)
#pragma unroll
      for (int r = 0; r < 4; ++r) {
        int trow = m * 16 + (lane >> 4) * 4 + r;
        int col = w * 64 + nf * 16 + (lane & 15);
        Zb[(size_t)trow * VC_ + col] = f2bf(acc[m][nf][r]);
      }
}

extern "C" void kernel_launch(void* const* d_in, const int* in_sizes, int n_in,
                              void* d_out, int out_size, void* d_ws,
                              size_t ws_size, hipStream_t stream) {
  const float* x      = (const float*)d_in[0];
  const float* W_ins  = (const float*)d_in[1];
  const float* b_ins  = (const float*)d_in[2];
  const float* att0   = (const float*)d_in[3];
  const float* W_outs = (const float*)d_in[4];
  const float* b_outs = (const float*)d_in[5];
  const float* W_ffs  = (const float*)d_in[6];
  const float* b_ffs  = (const float*)d_in[7];
  const float* W_inf  = (const float*)d_in[8];
  const float* b_inf  = (const float*)d_in[9];
  const float* W_inb  = (const float*)d_in[10];
  const float* b_inb  = (const float*)d_in[11];
  const float* W_outf = (const float*)d_in[12];
  const float* b_outf = (const float*)d_in[13];
  const float* W_outb = (const float*)d_in[14];
  const float* b_outb = (const float*)d_in[15];
  const float* W_fft  = (const float*)d_in[16];
  const float* b_fft  = (const float*)d_in[17];
  float* out = (float*)d_out;
  char* base = (char*)d_ws;

  // Workspace layout (bytes). Peak = 657,675,008 B ≈ 627.2 MiB.
  unsigned short* B0    = (unsigned short*)base;
  float*          y2    = (float*)(base + 314572800);           // 209.7 MB fp32
  unsigned short* projf = (unsigned short*)(base + 524288000);  // 104.9 MB bf16
  float*          Asp   = (float*)(base + 629145600);           // 0.48 MB
  float*          Af    = (float*)(base + 629625600);           // 12.6 MB
  float*          Ab    = (float*)(base + 642208512);           // 12.6 MB
  unsigned short* Wouts_h = (unsigned short*)(base + 654791424);
  unsigned short* Wouts_l = (unsigned short*)(base + 655184640);
  unsigned short* Wffs_h  = (unsigned short*)(base + 655577856);
  unsigned short* Wffs_l  = (unsigned short*)(base + 655708928);
  unsigned short* Woutf_h = (unsigned short*)(base + 655840000);
  unsigned short* Woutf_l = (unsigned short*)(base + 656233216);
  unsigned short* Woutb_h = (unsigned short*)(base + 656626432);
  unsigned short* Woutb_l = (unsigned short*)(base + 657019648);
  unsigned short* Wfft_h  = (unsigned short*)(base + 657412864);
  unsigned short* Wfft_l  = (unsigned short*)(base + 657543936);

  unsigned short* QKs  = B0;
  unsigned short* Y768 = B0;
  unsigned short* QKf  = B0;
  unsigned short* QKb  = B0 + 78643200;
  unsigned short* Zbuf = B0;

  // ---- weight prep (fragment-major bf16 hi/lo) ----
  prep_w_kernel<<<768, 256, 0, stream>>>(W_outs, 3, Wouts_h, Wouts_l);
  prep_w_kernel<<<256, 256, 0, stream>>>(W_ffs, 1, Wffs_h, Wffs_l);
  prep_w_kernel<<<768, 256, 0, stream>>>(W_outf, 3, Woutf_h, Woutf_l);
  prep_w_kernel<<<768, 256, 0, stream>>>(W_outb, 3, Woutb_h, Woutb_l);
  prep_w_kernel<<<256, 256, 0, stream>>>(W_fft, 1, Wfft_h, Wfft_l);

  // ---- spatial stage ----
  gemm_in_kernel<<<NT_, 128, 0, stream>>>(x, W_ins, b_ins, QKs);
  hipMemsetAsync(Asp, 0, (size_t)N_ * S_ * V_ * V_ * sizeof(float), stream);
  spatial_A_kernel<<<N_ * 8, 256, 0, stream>>>(QKs, Asp);
  norm_A_kernel<<<N_ * S_ * V_, 64, 0, stream>>>(Asp, att0);
  y768_kernel<<<NT_ / 2, 256, 0, stream>>>(x, Asp, Y768);
  mfma_proj_kernel<0><<<1600, 512, 0, stream>>>(
      Y768, Wouts_h, Wouts_l, b_outs, x, nullptr, Wffs_h, Wffs_l, b_ffs, y2,
      nullptr);
  // ---- temporal stage ----
  gemm_in_kernel<<<NT_, 128, 0, stream>>>(y2, W_inf, b_inf, QKf);
  gemm_in_kernel<<<NT_, 128, 0, stream>>>(y2, W_inb, b_inb, QKb);
  temporal_A_kernel<<<dim3(4, 3, 64), 256, 0, stream>>>(QKf, Af);
  temporal_A_kernel<<<dim3(4, 3, 64), 256, 0, stream>>>(QKb, Ab);
  norm_temporal_kernel<<<dim3(N_ * S_ * T_, 2), 64, 0, stream>>>(Af, Ab);
  // forward: Zf -> projf (Zbuf overlays dead QKf/QKb)
  temporal_z_mfma_kernel<<<dim3(25, 6, 64), 256, 0, stream>>>(Af, y2, Zbuf);
  mfma_proj_kernel<1><<<1600, 512, 0, stream>>>(
      Zbuf, Woutf_h, Woutf_l, b_outf, nullptr, nullptr, nullptr, nullptr,
      nullptr, nullptr, projf);
  // backward: Zb -> fused projection + final output
  temporal_z_mfma_kernel<<<dim3(25, 6, 64), 256, 0, stream>>>(Ab, y2, Zbuf);
  mfma_proj_kernel<2><<<1600, 512, 0, stream>>>(
      Zbuf, Woutb_h, Woutb_l, b_outb, y2, projf, Wfft_h, Wfft_l, b_fft, out,
      nullptr);
}

// Round 8
// 5364.479 us; speedup vs baseline: 1.2531x; 1.0225x over previous
//
#include <hip/hip_runtime.h>
#include <math.h>

// Problem constants (N,T,V,C,S,CI) = (64,128,25,256,3,64)
constexpr int N_ = 64, T_ = 128, V_ = 25, C_ = 256, S_ = 3;
constexpr int J_ = 384;          // 2*S*CI
constexpr int NT_ = N_ * T_;     // 8192
constexpr int VC_ = V_ * C_;     // 6400
constexpr int SC_ = S_ * C_;     // 768

__device__ __forceinline__ float gelu_f(float x) {
  return 0.5f * x * (1.0f + erff(x * 0.70710678118654752440f));
}
__device__ __forceinline__ float elup1(float x) {  // elu(x)+1
  return x > 0.0f ? x + 1.0f : __expf(x);
}
__device__ __forceinline__ float wave_sum(float x) {
#pragma unroll
  for (int off = 1; off < 64; off <<= 1) x += __shfl_xor(x, off, 64);
  return x;
}
// bf16 storage helpers (storage-only; all math fp32)
__device__ __forceinline__ float bf2f(unsigned short u) {
  union { unsigned int i; float f; } v; v.i = ((unsigned int)u) << 16;
  return v.f;
}
__device__ __forceinline__ unsigned short f2bf(float f) {
  union { float f; unsigned int i; } v; v.f = f;
  unsigned int r = v.i + 0x7fffu + ((v.i >> 16) & 1u);  // RNE
  return (unsigned short)(r >> 16);
}

// MFMA fragment types (verified layout: A row=lane&15, a[j] k=(lane>>4)*8+j;
// B col=lane&15, b[j] same k; C/D col=lane&15, row=(lane>>4)*4+reg)
typedef short bf16x8 __attribute__((ext_vector_type(8)));
typedef float f32x4 __attribute__((ext_vector_type(4)));

// ================= K1: out = bf16(elu(X @ W + b) + 1) ====================
__global__ __launch_bounds__(128) void gemm_in_kernel(
    const float* __restrict__ X, const float* __restrict__ W,
    const float* __restrict__ b, unsigned short* __restrict__ out) {
  __shared__ __align__(16) float xs[VC_];
  const int blk = blockIdx.x;
  const int tid = threadIdx.x;
  const float* Xb = X + (size_t)blk * VC_;
  for (int i = tid; i < VC_; i += 128) xs[i] = Xb[i];
  __syncthreads();
  const int lane = tid & 63, wave = tid >> 6;
  const int nr = wave == 0 ? 13 : 12;
  float acc[13][6];
#pragma unroll
  for (int r = 0; r < 13; ++r)
#pragma unroll
    for (int q = 0; q < 6; ++q) acc[r][q] = 0.f;
#pragma unroll 2
  for (int c = 0; c < C_; ++c) {
    float w[6];
#pragma unroll
    for (int q = 0; q < 6; ++q) w[q] = W[c * J_ + lane + 64 * q];
#pragma unroll
    for (int r = 0; r < 13; ++r) {
      int v = wave + 2 * r;
      float xv = xs[(v < V_ ? v : V_ - 1) * C_ + c];
#pragma unroll
      for (int q = 0; q < 6; ++q) acc[r][q] = fmaf(xv, w[q], acc[r][q]);
    }
  }
  float bj[6];
#pragma unroll
  for (int q = 0; q < 6; ++q) bj[q] = b[lane + 64 * q];
  unsigned short* Ob = out + (size_t)blk * (V_ * J_);
#pragma unroll
  for (int r = 0; r < 13; ++r) {
    int v = wave + 2 * r;
    if (r < nr) {
#pragma unroll
      for (int q = 0; q < 6; ++q)
        Ob[v * J_ + lane + 64 * q] = f2bf(elup1(acc[r][q] + bj[q]));
    }
  }
}

// ============ K2: spatial gram A[n,s,v,u] += sum_{t,c} q*k ===============
// LDS row stride padded 384 -> 390 (mod 32 = 6): k-operand reads across
// pu=0..24 hit >=16 distinct banks (worst 2-way, free).
constexpr int PJ_ = 390;  // padded LDS row stride (floats)
__global__ __launch_bounds__(256) void spatial_A_kernel(
    const unsigned short* __restrict__ QK, float* __restrict__ A) {
  __shared__ __align__(16) float qk[V_ * PJ_];  // 39.0 KB
  const int n = blockIdx.x >> 3, tq = blockIdx.x & 7;
  const int tid = threadIdx.x;
  float acc[3][3];
#pragma unroll
  for (int i = 0; i < 3; ++i)
#pragma unroll
    for (int s = 0; s < 3; ++s) acc[i][s] = 0.f;
  int pv[3], pu[3];
#pragma unroll
  for (int i = 0; i < 3; ++i) {
    int p = tid + 256 * i;
    pv[i] = p / V_;
    pu[i] = p - V_ * pv[i];
  }
  for (int tt = 0; tt < 16; ++tt) {
    int t = tq * 16 + tt;
    const ushort4* src4 =
        (const ushort4*)(QK + (size_t)(n * T_ + t) * (V_ * J_));
    __syncthreads();
    for (int i = tid; i < V_ * J_ / 4; i += 256) {
      int row = i / 96, wi = i - row * 96;  // 96 = J_/4
      ushort4 u = src4[i];
      float* d = qk + row * PJ_ + wi * 4;
      d[0] = bf2f(u.x);
      d[1] = bf2f(u.y);
      d[2] = bf2f(u.z);
      d[3] = bf2f(u.w);
    }
    __syncthreads();
#pragma unroll
    for (int i = 0; i < 3; ++i) {
      if (tid + 256 * i < 625) {
        const float* qr = qk + pv[i] * PJ_;
        const float* kr = qk + pu[i] * PJ_;
        for (int c = 0; c < 64; ++c) {
          float2 q01 = *(const float2*)(qr + c * 6);
          float q2 = qr[c * 6 + 2];
          float k0 = kr[c * 6 + 3];
          float2 k12 = *(const float2*)(kr + c * 6 + 4);
          acc[i][0] = fmaf(q01.x, k0, acc[i][0]);
          acc[i][1] = fmaf(q01.y, k12.x, acc[i][1]);
          acc[i][2] = fmaf(q2, k12.y, acc[i][2]);
        }
      }
    }
  }
#pragma unroll
  for (int i = 0; i < 3; ++i)
    if (tid + 256 * i < 625) {
#pragma unroll
      for (int s = 0; s < 3; ++s)
        atomicAdd(&A[((n * S_ + s) * V_ + pv[i]) * V_ + pu[i]], acc[i][s]);
    }
}

// ======= K3: A = A / rowsum + att0 ========================================
__global__ __launch_bounds__(64) void norm_A_kernel(
    float* __restrict__ A, const float* __restrict__ att0) {
  const int row = blockIdx.x;           // (n*S+s)*V + v
  const int sv = row % (S_ * V_);       // s*V + v
  const int lane = threadIdx.x;
  float val = (lane < V_) ? A[row * V_ + lane] : 0.f;
  float sum = wave_sum(val);
  if (lane < V_) A[row * V_ + lane] = val / sum + att0[sv * V_ + lane];
}

// ====== K4a: y768[nt, v, s, c] = bf16(sum_u A[n,s,v,u] * x[nt,u,c]) ======
__global__ __launch_bounds__(256) void y768_kernel(
    const float* __restrict__ X, const float* __restrict__ A,
    unsigned short* __restrict__ Y768) {
  __shared__ __align__(16) float xs[2 * VC_];      // 51.2 KB
  __shared__ __align__(16) float As[S_ * V_ * 28]; // padded rows
  const int nt0 = blockIdx.x * 2;
  const int n = nt0 >> 7;
  const int tid = threadIdx.x;  // = c
  for (int i = tid; i < 2 * VC_; i += 256)
    xs[i] = X[(size_t)nt0 * VC_ + i];
  const float* Abase = A + n * (S_ * V_ * V_);
  for (int i = tid; i < S_ * V_ * V_; i += 256) {
    int r = i / V_, u = i - r * V_;
    As[r * 28 + u] = Abase[i];
  }
  __syncthreads();
  float xu0[V_], xu1[V_];
#pragma unroll
  for (int u = 0; u < V_; ++u) {
    xu0[u] = xs[u * C_ + tid];
    xu1[u] = xs[VC_ + u * C_ + tid];
  }
  unsigned short* Ob0 = Y768 + (size_t)nt0 * (V_ * SC_);
  unsigned short* Ob1 = Ob0 + (V_ * SC_);
  for (int v = 0; v < V_; ++v) {
#pragma unroll
    for (int s = 0; s < 3; ++s) {
      const float* Ar = As + (s * V_ + v) * 28;
      float a0 = 0.f, a1 = 0.f;
#pragma unroll
      for (int u = 0; u < V_; ++u) {
        float av = Ar[u];
        a0 = fmaf(av, xu0[u], a0);
        a1 = fmaf(av, xu1[u], a1);
      }
      Ob0[(v * S_ + s) * C_ + tid] = f2bf(a0);
      Ob1[(v * S_ + s) * C_ + tid] = f2bf(a1);
    }
  }
}

// ====== K5: weight prep — fragment-major bf16 hi/lo =====================
__global__ __launch_bounds__(256) void prep_w_kernel(
    const float* __restrict__ W, int nS, unsigned short* __restrict__ hi,
    unsigned short* __restrict__ lo) {
  int idx = blockIdx.x * 256 + threadIdx.x;
  int j = idx & 7, l = (idx >> 3) & 63, nfg = (idx >> 9) & 15,
      kstep = (idx >> 13) & 7, s = idx >> 16;
  int col = nfg * 16 + (l & 15);
  int k = kstep * 32 + (l >> 4) * 8 + j;
  float v = W[(k * nS + s) * 256 + col];
  unsigned short h = f2bf(v);
  hi[idx] = h;
  lo[idx] = f2bf(v - bf2f(h));
}

// ====== MFMA projection kernel (8 waves / 512 threads) ===================
// MODE 0: spatial_out  g=gelu(X+ln(Y768@Wo+bo)); out=gelu(X+ln(g@Wf+bf)) f32
// MODE 1: proj_f       out = bf16(ln(Z@Wo+bo))
// MODE 2: proj_final_b g=gelu(Y+Pf+ln(Z@Wo+bo)); out=gelu(Y+ln(g@Wt+bt)) f32
// r7/r8: A-tile staging via global_load_lds (zero VGPRs held; r6's streg[8]
// held 32 regs across a barrier -> allocator spilled ~420 MB/dispatch to
// scratch). K staged in 128-chunks, LDS double-buffered (2x32 KB), loads
// for stage t+1 issued at start of stage t (one barrier/stage drains them).
// LN epilogues compute mu/rstd inline from Red (no muv/rsv arrays).
// Peak live ~110 regs -> clean fit in the 128-VGPR / 2-blocks-per-CU tier.
// (r8 = r7 resubmission: r7 bench died at container level with no kernel
// verdict; staging layout re-audited against m104/m108 wave-uniform-dest
// rule and in-bounds checked for all modes.)
#define LOADB_(dh, dl, Wh, Wl, sk)                                         \
  {                                                                        \
    _Pragma("unroll") for (int nf_ = 0; nf_ < 4; ++nf_) {                  \
      int wo_ = ((sk) * 16 + (wc * 4 + nf_)) * 512 + lane * 8;             \
      dh[nf_] = *(const bf16x8*)((Wh) + wo_);                              \
      dl[nf_] = *(const bf16x8*)((Wl) + wo_);                              \
    }                                                                      \
  }

// GEMM1 MFMA step: ks in [0,4), reads chunk (ks*8 + wr*4+m) of `buf`.
#define MFMA1_(ks, BH, BL)                                                 \
  {                                                                        \
    _Pragma("unroll") for (int m_ = 0; m_ < 4; ++m_) {                     \
      bf16x8 af_ = *(const bf16x8*)&buf[(((ks) * 8 + (wr * 4 + m_)) * 64 + \
                                        lane) * 8];                        \
      _Pragma("unroll") for (int nf_ = 0; nf_ < 4; ++nf_) {                \
        acc[m_][nf_] = __builtin_amdgcn_mfma_f32_16x16x32_bf16(            \
            af_, BH[nf_], acc[m_][nf_], 0, 0, 0);                          \
        acc[m_][nf_] = __builtin_amdgcn_mfma_f32_16x16x32_bf16(            \
            af_, BL[nf_], acc[m_][nf_], 0, 0, 0);                          \
      }                                                                    \
    }                                                                      \
  }

#define MFMA2_(ks, BH, BL)                                                 \
  {                                                                        \
    _Pragma("unroll") for (int m_ = 0; m_ < 4; ++m_) {                     \
      int row_ = wr * 64 + m_ * 16 + (lane & 15);                          \
      int slot_ = ((ks) * 4 + (lane >> 4)) ^ (row_ & 7);                   \
      bf16x8 af_ =                                                         \
          *(const bf16x8*)((const char*)Gsh + row_ * 512 + slot_ * 16);    \
      _Pragma("unroll") for (int nf_ = 0; nf_ < 4; ++nf_) {                \
        acc[m_][nf_] = __builtin_amdgcn_mfma_f32_16x16x32_bf16(            \
            af_, BH[nf_], acc[m_][nf_], 0, 0, 0);                          \
        acc[m_][nf_] = __builtin_amdgcn_mfma_f32_16x16x32_bf16(            \
            af_, BL[nf_], acc[m_][nf_], 0, 0, 0);                          \
      }                                                                    \
    }                                                                      \
  }

template <int MODE>
__global__ __launch_bounds__(512, 2) void mfma_proj_kernel(
    const unsigned short* __restrict__ A,    // bf16 GEMM1 input
    const unsigned short* __restrict__ W1h, const unsigned short* __restrict__ W1l,
    const float* __restrict__ b1,
    const float* __restrict__ Res,           // fp32 residual (X or y2)
    const unsigned short* __restrict__ Pf,   // bf16 (MODE 2)
    const unsigned short* __restrict__ W2h, const unsigned short* __restrict__ W2l,
    const float* __restrict__ b2,
    float* __restrict__ OutF,                // MODE 0/2
    unsigned short* __restrict__ OutB) {     // MODE 1
  __shared__ __align__(16) unsigned short Ash[2][16384];  // 2 x 32 KB A-tile bufs
  __shared__ __align__(16) float Red[128][8];             // 4 KB LN partials
  unsigned short* Gsh = &Ash[0][0];                       // 64 KB flat for G
  const int tid = threadIdx.x, lane = tid & 63, w = tid >> 6;
  const int wr = w >> 2, wc = w & 3;
  const int bid = blockIdx.x;
  const int n = bid / 25, mt = bid - n * 25;
  const int row0 = n * 3200 + mt * 128;  // flat row (nt*25+v) for Res/Pf/Out
  size_t abase, asstride;
  int arstride;
  if (MODE == 0) {  // Y768: [flat_row][s*256 + c], row stride 768
    abase = (size_t)row0 * 768; arstride = 768; asstride = 256;
  } else {          // Z: [n][s][flat_tv][c]
    abase = (size_t)n * ((size_t)S_ * T_ * VC_) + (size_t)(mt * 128) * 256;
    arstride = 256; asstride = (size_t)T_ * VC_;
  }

  // issue one K=128 stage (32 chunks of 1 KB) via global_load_lds: chunk
  // c = ks*8+mg; lane reads row mg*16+(lane&15), k = ks*32+(lane>>4)*8 (+base)
  auto stage_loads = [&](int t) {
    const int sblk = t >> 1;
    const int kbase = (t & 1) * 128;
#pragma unroll
    for (int i = 0; i < 4; ++i) {
      int c = w * 4 + i;
      int ks = c >> 3, mg = c & 7;
      int row = mg * 16 + (lane & 15);
      int koff = kbase + ks * 32 + (lane >> 4) * 8;
      const unsigned short* src = A + abase + (size_t)sblk * asstride +
                                  (size_t)row * arstride + koff;
      __builtin_amdgcn_global_load_lds(
          (const __attribute__((address_space(1))) unsigned int*)src,
          (__attribute__((address_space(3))) unsigned int*)&Ash[t & 1][c * 512],
          16, 0, 0);
    }
  };

  f32x4 acc[4][4];
#pragma unroll
  for (int m = 0; m < 4; ++m)
#pragma unroll
    for (int nf = 0; nf < 4; ++nf) acc[m][nf] = (f32x4){0.f, 0.f, 0.f, 0.f};

  bf16x8 bh[4], bl[4];

  // ---------------- GEMM1: K = 768 as 6 stages of 128 ----------------
  stage_loads(0);
  __syncthreads();  // drain stage-0 loads
  for (int t = 0; t < 6; ++t) {
    if (t < 5) stage_loads(t + 1);
    const unsigned short* buf = &Ash[t & 1][0];
    LOADB_(bh, bl, W1h, W1l, t * 4);
#pragma unroll
    for (int ks = 0; ks < 4; ++ks) {
      MFMA1_(ks, bh, bl);
      if (ks < 3) LOADB_(bh, bl, W1h, W1l, t * 4 + ks + 1);
    }
    __syncthreads();  // drains next-stage loads; releases buf for t+2
  }

  // ---------------- Epilogue 1: per-row LayerNorm stats ----------------
  float b1c[4];
#pragma unroll
  for (int nf = 0; nf < 4; ++nf) b1c[nf] = b1[wc * 64 + nf * 16 + (lane & 15)];
#pragma unroll
  for (int m = 0; m < 4; ++m)
#pragma unroll
    for (int r = 0; r < 4; ++r) {
      float su = 0.f, sq = 0.f;
#pragma unroll
      for (int nf = 0; nf < 4; ++nf) {
        float v = acc[m][nf][r] + b1c[nf];
        su += v; sq += v * v;
      }
#pragma unroll
      for (int off = 1; off < 16; off <<= 1) {
        su += __shfl_xor(su, off, 64);
        sq += __shfl_xor(sq, off, 64);
      }
      if ((lane & 15) == 0) {
        int row = wr * 64 + m * 16 + (lane >> 4) * 4 + r;
        Red[row][2 * wc + 0] = su;
        Red[row][2 * wc + 1] = sq;
      }
    }
  __syncthreads();

  if (MODE == 1) {  // proj_f: out = bf16(ln(vals))
#pragma unroll
    for (int m = 0; m < 4; ++m)
#pragma unroll
      for (int r = 0; r < 4; ++r) {
        int row = wr * 64 + m * 16 + (lane >> 4) * 4 + r;
        f32x4 p0 = *(const f32x4*)&Red[row][0];
        f32x4 p1 = *(const f32x4*)&Red[row][4];
        float mu = (p0.x + p0.z + p1.x + p1.z) * (1.f / 256.f);
        float sq = (p0.y + p0.w + p1.y + p1.w) * (1.f / 256.f);
        float rsd = rsqrtf(fmaxf(sq - mu * mu, 0.f) + 1e-5f);
#pragma unroll
        for (int nf = 0; nf < 4; ++nf) {
          int col = wc * 64 + nf * 16 + (lane & 15);
          OutB[(size_t)(row0 + row) * 256 + col] =
              f2bf((acc[m][nf][r] + b1c[nf] - mu) * rsd);
        }
      }
    return;
  }

  // g = gelu(res [+pf] + ln(vals)) -> bf16 in XOR-swizzled LDS (reuses Ash)
#pragma unroll
  for (int m = 0; m < 4; ++m)
#pragma unroll
    for (int r = 0; r < 4; ++r) {
      int row = wr * 64 + m * 16 + (lane >> 4) * 4 + r;
      f32x4 p0 = *(const f32x4*)&Red[row][0];
      f32x4 p1 = *(const f32x4*)&Red[row][4];
      float mu = (p0.x + p0.z + p1.x + p1.z) * (1.f / 256.f);
      float sq = (p0.y + p0.w + p1.y + p1.w) * (1.f / 256.f);
      float rsd = rsqrtf(fmaxf(sq - mu * mu, 0.f) + 1e-5f);
#pragma unroll
      for (int nf = 0; nf < 4; ++nf) {
        int col = wc * 64 + nf * 16 + (lane & 15);
        float resv = Res[(size_t)(row0 + row) * 256 + col];
        if (MODE == 2) resv += bf2f(Pf[(size_t)(row0 + row) * 256 + col]);
        float gv = gelu_f(resv + (acc[m][nf][r] + b1c[nf] - mu) * rsd);
        int slot = (col >> 3) ^ (row & 7);
        *(unsigned short*)((char*)Gsh + row * 512 + slot * 16 + (col & 7) * 2) =
            f2bf(gv);
      }
    }
  __syncthreads();

  // ---------------- GEMM2: K = 256 from Gsh ----------------
#pragma unroll
  for (int m = 0; m < 4; ++m)
#pragma unroll
    for (int nf = 0; nf < 4; ++nf) acc[m][nf] = (f32x4){0.f, 0.f, 0.f, 0.f};
  LOADB_(bh, bl, W2h, W2l, 0);
#pragma unroll 2
  for (int ks = 0; ks < 8; ++ks) {
    MFMA2_(ks, bh, bl);
    if (ks < 7) LOADB_(bh, bl, W2h, W2l, ks + 1);
  }

  // ---------------- Epilogue 2 ----------------
  float b2c[4];
#pragma unroll
  for (int nf = 0; nf < 4; ++nf) b2c[nf] = b2[wc * 64 + nf * 16 + (lane & 15)];
  __syncthreads();  // Red reads of epilogue 1 done everywhere
#pragma unroll
  for (int m = 0; m < 4; ++m)
#pragma unroll
    for (int r = 0; r < 4; ++r) {
      float su = 0.f, sq = 0.f;
#pragma unroll
      for (int nf = 0; nf < 4; ++nf) {
        float v = acc[m][nf][r] + b2c[nf];
        su += v; sq += v * v;
      }
#pragma unroll
      for (int off = 1; off < 16; off <<= 1) {
        su += __shfl_xor(su, off, 64);
        sq += __shfl_xor(sq, off, 64);
      }
      if ((lane & 15) == 0) {
        int row = wr * 64 + m * 16 + (lane >> 4) * 4 + r;
        Red[row][2 * wc + 0] = su;
        Red[row][2 * wc + 1] = sq;
      }
    }
  __syncthreads();
#pragma unroll
  for (int m = 0; m < 4; ++m)
#pragma unroll
    for (int r = 0; r < 4; ++r) {
      int row = wr * 64 + m * 16 + (lane >> 4) * 4 + r;
      f32x4 p0 = *(const f32x4*)&Red[row][0];
      f32x4 p1 = *(const f32x4*)&Red[row][4];
      float mu = (p0.x + p0.z + p1.x + p1.z) * (1.f / 256.f);
      float sq = (p0.y + p0.w + p1.y + p1.w) * (1.f / 256.f);
      float rsd = rsqrtf(fmaxf(sq - mu * mu, 0.f) + 1e-5f);
#pragma unroll
      for (int nf = 0; nf < 4; ++nf) {
        int col = wc * 64 + nf * 16 + (lane & 15);
        float resv = Res[(size_t)(row0 + row) * 256 + col];
        OutF[(size_t)(row0 + row) * 256 + col] =
            gelu_f(resv + (acc[m][nf][r] + b2c[nf] - mu) * rsd);
      }
    }
}

// ====== K6: Af[n,s,t,k] = sum_{v,c} q[t]*k[k]  (unnormalized) ============
__global__ __launch_bounds__(256) void temporal_A_kernel(
    const unsigned short* __restrict__ QK, float* __restrict__ A) {
  __shared__ __align__(16) float Qs[32 * 68];
  __shared__ __align__(16) float Ks[128 * 68];
  const int tt = blockIdx.x, s = blockIdx.y, n = blockIdx.z;
  const int tid = threadIdx.x;
  const int kg = tid & 15;   // k = kg + 16*j
  const int tp = tid >> 4;   // rows tp*2, tp*2+1
  float acc[2][8];
#pragma unroll
  for (int r = 0; r < 2; ++r)
#pragma unroll
    for (int j = 0; j < 8; ++j) acc[r][j] = 0.f;
  for (int v = 0; v < V_; ++v) {
    __syncthreads();
    for (int i = tid; i < 128 * 64; i += 256) {
      int k = i >> 6, c = i & 63;
      Ks[k * 68 + c] =
          bf2f(QK[(size_t)((n * T_ + k) * V_ + v) * J_ + c * 6 + 3 + s]);
    }
    for (int i = tid; i < 32 * 64; i += 256) {
      int t = i >> 6, c = i & 63;
      Qs[t * 68 + c] =
          bf2f(QK[(size_t)((n * T_ + tt * 32 + t) * V_ + v) * J_ + c * 6 + s]);
    }
    __syncthreads();
    for (int c = 0; c < 64; c += 4) {
      float4 q0 = *(const float4*)(Qs + (tp * 2 + 0) * 68 + c);
      float4 q1 = *(const float4*)(Qs + (tp * 2 + 1) * 68 + c);
#pragma unroll
      for (int j = 0; j < 8; ++j) {
        float4 kv = *(const float4*)(Ks + (kg + 16 * j) * 68 + c);
        acc[0][j] = fmaf(q0.x, kv.x, fmaf(q0.y, kv.y,
                    fmaf(q0.z, kv.z, fmaf(q0.w, kv.w, acc[0][j]))));
        acc[1][j] = fmaf(q1.x, kv.x, fmaf(q1.y, kv.y,
                    fmaf(q1.z, kv.z, fmaf(q1.w, kv.w, acc[1][j]))));
      }
    }
  }
  float* Ob = A + ((size_t)(n * S_ + s) * T_ + tt * 32) * T_;
#pragma unroll
  for (int r = 0; r < 2; ++r)
#pragma unroll
    for (int j = 0; j < 8; ++j)
      Ob[(tp * 2 + r) * T_ + kg + 16 * j] = acc[r][j];
}

// ====== K6b: mask (tril/triu) + row-normalize Af and Ab ==================
__global__ __launch_bounds__(64) void norm_temporal_kernel(
    float* __restrict__ Af, float* __restrict__ Ab) {
  const int row = blockIdx.x;  // (n*S+s)*T + t
  const int t = row & (T_ - 1);
  const int lane = threadIdx.x;
  float* A = blockIdx.y == 0 ? Af : Ab;
  const bool fw = blockIdx.y == 0;
  float v0 = A[(size_t)row * T_ + lane];
  float v1 = A[(size_t)row * T_ + lane + 64];
  v0 *= fw ? (lane <= t ? 1.f : 0.f) : (lane >= t ? 1.f : 0.f);
  v1 *= fw ? (lane + 64 <= t ? 1.f : 0.f) : (lane + 64 >= t ? 1.f : 0.f);
  float inv = 1.f / wave_sum(v0 + v1);
  A[(size_t)row * T_ + lane] = v0 * inv;
  A[(size_t)row * T_ + lane + 64] = v1 * inv;
}

// ====== K7: Z[n,s,t,vc] = bf16(sum_k A[n,s,t,k] * Y[n,k,vc]) — MFMA ======
__global__ __launch_bounds__(256, 3) void temporal_z_mfma_kernel(
    const float* __restrict__ A, const float* __restrict__ Y,
    unsigned short* __restrict__ Z) {
  __shared__ __align__(16) unsigned short Ahs[4 * 4 * 64 * 8];  // 16 KB
  __shared__ __align__(16) unsigned short Als[4 * 4 * 64 * 8];  // 16 KB
  __shared__ __align__(16) unsigned short Ys[16 * 64 * 8];      // 16 KB
  const int cb = blockIdx.x;                     // col block of 256
  const int s = blockIdx.y >> 1, rt = blockIdx.y & 1;
  const int n = blockIdx.z;
  const int tid = threadIdx.x, lane = tid & 63, w = tid >> 6;
  const int t0 = rt * 64;
  const float* Atile = A + ((size_t)(n * S_ + s) * T_ + t0) * T_;  // 64x128
  // convert A tile to frag-major bf16 hi/lo
  for (int i = tid; i < 64 * 128; i += 256) {
    int r = i >> 7, k = i & 127;
    float av = Atile[r * T_ + k];
    unsigned short h = f2bf(av);
    unsigned short l = f2bf(av - bf2f(h));
    int idx = ((((k >> 5) * 4 + (r >> 4)) * 64 + (r & 15) + 16 * ((k >> 3) & 3))
               << 3) | (k & 7);
    Ahs[idx] = h;
    Als[idx] = l;
  }
  f32x4 acc[4][4];
#pragma unroll
  for (int m = 0; m < 4; ++m)
#pragma unroll
    for (int nf = 0; nf < 4; ++nf) acc[m][nf] = (f32x4){0.f, 0.f, 0.f, 0.f};
  const float* Yb = Y + (size_t)n * (T_ * VC_) + cb * 256;
  for (int kstep = 0; kstep < 4; ++kstep) {
    __syncthreads();  // A-conversion done (iter 0) / prior Ys reads done
    for (int i = tid; i < 32 * 256; i += 256) {
      int kl = i >> 8, c = i & 255;
      float yv = Yb[(size_t)(kstep * 32 + kl) * VC_ + c];
      Ys[(((c >> 4) * 64 + (c & 15) + 16 * ((kl >> 3) & 3)) << 3) | (kl & 7)] =
          f2bf(yv);
    }
    __syncthreads();
    bf16x8 bv[4];
#pragma unroll
    for (int nf = 0; nf < 4; ++nf)
      bv[nf] = *(const bf16x8*)&Ys[((w * 4 + nf) * 64 + lane) * 8];
    bf16x8 af[4];
#pragma unroll
    for (int m = 0; m < 4; ++m)
      af[m] = *(const bf16x8*)&Ahs[((kstep * 4 + m) * 64 + lane) * 8];
#pragma unroll
    for (int nf = 0; nf < 4; ++nf)
#pragma unroll
      for (int m = 0; m < 4; ++m)
        acc[m][nf] = __builtin_amdgcn_mfma_f32_16x16x32_bf16(af[m], bv[nf], acc[m][nf], 0, 0, 0);
#pragma unroll
    for (int m = 0; m < 4; ++m)
      af[m] = *(const bf16x8*)&Als[((kstep * 4 + m) * 64 + lane) * 8];
#pragma unroll
    for (int nf = 0; nf < 4; ++nf)
#pragma unroll
      for (int m = 0; m < 4; ++m)
        acc[m][nf] = __builtin_amdgcn_mfma_f32_16x16x32_bf16(af[m], bv[nf], acc[m][nf], 0, 0, 0);
  }
  unsigned short* Zb = Z + ((size_t)(n * S_ + s) * T_ + t0) * VC_ + cb * 256;
#pragma unroll
  for (int m = 0; m < 4; ++m)
#pragma unroll
    for (int nf = 0; nf < 4; ++nf)
#pragma unroll
      for (int r = 0; r < 4; ++r) {
        int trow = m * 16 + (lane >> 4) * 4 + r;
        int col = w * 64 + nf * 16 + (lane & 15);
        Zb[(size_t)trow * VC_ + col] = f2bf(acc[m][nf][r]);
      }
}

extern "C" void kernel_launch(void* const* d_in, const int* in_sizes, int n_in,
                              void* d_out, int out_size, void* d_ws,
                              size_t ws_size, hipStream_t stream) {
  const float* x      = (const float*)d_in[0];
  const float* W_ins  = (const float*)d_in[1];
  const float* b_ins  = (const float*)d_in[2];
  const float* att0   = (const float*)d_in[3];
  const float* W_outs = (const float*)d_in[4];
  const float* b_outs = (const float*)d_in[5];
  const float* W_ffs  = (const float*)d_in[6];
  const float* b_ffs  = (const float*)d_in[7];
  const float* W_inf  = (const float*)d_in[8];
  const float* b_inf  = (const float*)d_in[9];
  const float* W_inb  = (const float*)d_in[10];
  const float* b_inb  = (const float*)d_in[11];
  const float* W_outf = (const float*)d_in[12];
  const float* b_outf = (const float*)d_in[13];
  const float* W_outb = (const float*)d_in[14];
  const float* b_outb = (const float*)d_in[15];
  const float* W_fft  = (const float*)d_in[16];
  const float* b_fft  = (const float*)d_in[17];
  float* out = (float*)d_out;
  char* base = (char*)d_ws;

  // Workspace layout (bytes). Peak = 657,675,008 B ≈ 627.2 MiB.
  unsigned short* B0    = (unsigned short*)base;
  float*          y2    = (float*)(base + 314572800);           // 209.7 MB fp32
  unsigned short* projf = (unsigned short*)(base + 524288000);  // 104.9 MB bf16
  float*          Asp   = (float*)(base + 629145600);           // 0.48 MB
  float*          Af    = (float*)(base + 629625600);           // 12.6 MB
  float*          Ab    = (float*)(base + 642208512);           // 12.6 MB
  unsigned short* Wouts_h = (unsigned short*)(base + 654791424);
  unsigned short* Wouts_l = (unsigned short*)(base + 655184640);
  unsigned short* Wffs_h  = (unsigned short*)(base + 655577856);
  unsigned short* Wffs_l  = (unsigned short*)(base + 655708928);
  unsigned short* Woutf_h = (unsigned short*)(base + 655840000);
  unsigned short* Woutf_l = (unsigned short*)(base + 656233216);
  unsigned short* Woutb_h = (unsigned short*)(base + 656626432);
  unsigned short* Woutb_l = (unsigned short*)(base + 657019648);
  unsigned short* Wfft_h  = (unsigned short*)(base + 657412864);
  unsigned short* Wfft_l  = (unsigned short*)(base + 657543936);

  unsigned short* QKs  = B0;
  unsigned short* Y768 = B0;
  unsigned short* QKf  = B0;
  unsigned short* QKb  = B0 + 78643200;
  unsigned short* Zbuf = B0;

  // ---- weight prep (fragment-major bf16 hi/lo) ----
  prep_w_kernel<<<768, 256, 0, stream>>>(W_outs, 3, Wouts_h, Wouts_l);
  prep_w_kernel<<<256, 256, 0, stream>>>(W_ffs, 1, Wffs_h, Wffs_l);
  prep_w_kernel<<<768, 256, 0, stream>>>(W_outf, 3, Woutf_h, Woutf_l);
  prep_w_kernel<<<768, 256, 0, stream>>>(W_outb, 3, Woutb_h, Woutb_l);
  prep_w_kernel<<<256, 256, 0, stream>>>(W_fft, 1, Wfft_h, Wfft_l);

  // ---- spatial stage ----
  gemm_in_kernel<<<NT_, 128, 0, stream>>>(x, W_ins, b_ins, QKs);
  hipMemsetAsync(Asp, 0, (size_t)N_ * S_ * V_ * V_ * sizeof(float), stream);
  spatial_A_kernel<<<N_ * 8, 256, 0, stream>>>(QKs, Asp);
  norm_A_kernel<<<N_ * S_ * V_, 64, 0, stream>>>(Asp, att0);
  y768_kernel<<<NT_ / 2, 256, 0, stream>>>(x, Asp, Y768);
  mfma_proj_kernel<0><<<1600, 512, 0, stream>>>(
      Y768, Wouts_h, Wouts_l, b_outs, x, nullptr, Wffs_h, Wffs_l, b_ffs, y2,
      nullptr);
  // ---- temporal stage ----
  gemm_in_kernel<<<NT_, 128, 0, stream>>>(y2, W_inf, b_inf, QKf);
  gemm_in_kernel<<<NT_, 128, 0, stream>>>(y2, W_inb, b_inb, QKb);
  temporal_A_kernel<<<dim3(4, 3, 64), 256, 0, stream>>>(QKf, Af);
  temporal_A_kernel<<<dim3(4, 3, 64), 256, 0, stream>>>(QKb, Ab);
  norm_temporal_kernel<<<dim3(N_ * S_ * T_, 2), 64, 0, stream>>>(Af, Ab);
  // forward: Zf -> projf (Zbuf overlays dead QKf/QKb)
  temporal_z_mfma_kernel<<<dim3(25, 6, 64), 256, 0, stream>>>(Af, y2, Zbuf);
  mfma_proj_kernel<1><<<1600, 512, 0, stream>>>(
      Zbuf, Woutf_h, Woutf_l, b_outf, nullptr, nullptr, nullptr, nullptr,
      nullptr, nullptr, projf);
  // backward: Zb -> fused projection + final output
  temporal_z_mfma_kernel<<<dim3(25, 6, 64), 256, 0, stream>>>(Ab, y2, Zbuf);
  mfma_proj_kernel<2><<<1600, 512, 0, stream>>>(
      Zbuf, Woutb_h, Woutb_l, b_outb, y2, projf, Wfft_h, Wfft_l, b_fft, out,
      nullptr);
}

// Round 9
// 4233.943 us; speedup vs baseline: 1.5877x; 1.2670x over previous
//
#include <hip/hip_runtime.h>
#include <math.h>

// Problem constants (N,T,V,C,S,CI) = (64,128,25,256,3,64)
constexpr int N_ = 64, T_ = 128, V_ = 25, C_ = 256, S_ = 3;
constexpr int J_ = 384;          // 2*S*CI
constexpr int NT_ = N_ * T_;     // 8192
constexpr int VC_ = V_ * C_;     // 6400
constexpr int SC_ = S_ * C_;     // 768

__device__ __forceinline__ float gelu_f(float x) {
  return 0.5f * x * (1.0f + erff(x * 0.70710678118654752440f));
}
__device__ __forceinline__ float elup1(float x) {  // elu(x)+1
  return x > 0.0f ? x + 1.0f : __expf(x);
}
__device__ __forceinline__ float wave_sum(float x) {
#pragma unroll
  for (int off = 1; off < 64; off <<= 1) x += __shfl_xor(x, off, 64);
  return x;
}
// bf16 storage helpers (storage-only; all math fp32)
__device__ __forceinline__ float bf2f(unsigned short u) {
  union { unsigned int i; float f; } v; v.i = ((unsigned int)u) << 16;
  return v.f;
}
__device__ __forceinline__ unsigned short f2bf(float f) {
  union { float f; unsigned int i; } v; v.f = f;
  unsigned int r = v.i + 0x7fffu + ((v.i >> 16) & 1u);  // RNE
  return (unsigned short)(r >> 16);
}

// MFMA fragment types (verified layout: A row=lane&15, a[j] k=(lane>>4)*8+j;
// B col=lane&15, b[j] same k; C/D col=lane&15, row=(lane>>4)*4+reg)
typedef short bf16x8 __attribute__((ext_vector_type(8)));
typedef float f32x4 __attribute__((ext_vector_type(4)));

// ====== K1 (r9): MFMA gemm_in — out = bf16(elu(X @ W + b) + 1) ===========
// X fp32 (204800 x 256) converted per-block to bf16 hi/lo in LDS (pattern
// validated in temporal_z_mfma); W frag-major bf16 hi/lo; 3-product
// accumulation XhWh+XhWl+XlWh (XlWl ~2^-16 rel, dropped). Block = 64 rows
// x 384 cols; 8 waves each own 64 x 48 (acc[4][3] = 48 regs; peak live
// ~100 -> 128-VGPR tier, no spill). K=256 fully LDS-resident (64 KB).
__global__ __launch_bounds__(512, 2) void gemm_in_mfma_kernel(
    const float* __restrict__ X, const unsigned short* __restrict__ Wh,
    const unsigned short* __restrict__ Wl, const float* __restrict__ b,
    unsigned short* __restrict__ out) {
  __shared__ __align__(16) unsigned short Xh[64 * 256];  // 32 KB
  __shared__ __align__(16) unsigned short Xl[64 * 256];  // 32 KB
  const int tid = threadIdx.x, lane = tid & 63, w = tid >> 6;  // w = wc
  const int row0 = blockIdx.x * 64;
  // --- convert X tile (64x256 fp32) to frag-major bf16 hi/lo in LDS ---
#pragma unroll
  for (int i = 0; i < 4; ++i) {
    int c2 = w * 4 + i;                    // frag chunk = ks*4 + m
    int row = (c2 & 3) * 16 + (lane & 15);
    int koff = (c2 >> 2) * 32 + (lane >> 4) * 8;
    const float* src = X + (size_t)(row0 + row) * 256 + koff;
    float4 a = *(const float4*)src;
    float4 c = *(const float4*)(src + 4);
    float v[8] = {a.x, a.y, a.z, a.w, c.x, c.y, c.z, c.w};
    bf16x8 hv, lv;
#pragma unroll
    for (int e = 0; e < 8; ++e) {
      unsigned short h = f2bf(v[e]);
      hv[e] = (short)h;
      lv[e] = (short)f2bf(v[e] - bf2f(h));
    }
    *(bf16x8*)&Xh[(c2 * 64 + lane) * 8] = hv;
    *(bf16x8*)&Xl[(c2 * 64 + lane) * 8] = lv;
  }
  __syncthreads();

  f32x4 acc[4][3];
#pragma unroll
  for (int m = 0; m < 4; ++m)
#pragma unroll
    for (int nf = 0; nf < 3; ++nf) acc[m][nf] = (f32x4){0.f, 0.f, 0.f, 0.f};

  bf16x8 bh[3], bl[3];
#pragma unroll
  for (int nf = 0; nf < 3; ++nf) {
    int wo = (0 * 24 + w * 3 + nf) * 512 + lane * 8;
    bh[nf] = *(const bf16x8*)(Wh + wo);
    bl[nf] = *(const bf16x8*)(Wl + wo);
  }
#pragma unroll 2
  for (int ks = 0; ks < 8; ++ks) {
#pragma unroll
    for (int m = 0; m < 4; ++m) {
      bf16x8 ah = *(const bf16x8*)&Xh[((ks * 4 + m) * 64 + lane) * 8];
      bf16x8 al = *(const bf16x8*)&Xl[((ks * 4 + m) * 64 + lane) * 8];
#pragma unroll
      for (int nf = 0; nf < 3; ++nf) {
        acc[m][nf] = __builtin_amdgcn_mfma_f32_16x16x32_bf16(ah, bh[nf], acc[m][nf], 0, 0, 0);
        acc[m][nf] = __builtin_amdgcn_mfma_f32_16x16x32_bf16(ah, bl[nf], acc[m][nf], 0, 0, 0);
        acc[m][nf] = __builtin_amdgcn_mfma_f32_16x16x32_bf16(al, bh[nf], acc[m][nf], 0, 0, 0);
      }
    }
    if (ks < 7) {
#pragma unroll
      for (int nf = 0; nf < 3; ++nf) {
        int wo = ((ks + 1) * 24 + w * 3 + nf) * 512 + lane * 8;
        bh[nf] = *(const bf16x8*)(Wh + wo);
        bl[nf] = *(const bf16x8*)(Wl + wo);
      }
    }
  }
  float bc[3];
#pragma unroll
  for (int nf = 0; nf < 3; ++nf) bc[nf] = b[w * 48 + nf * 16 + (lane & 15)];
#pragma unroll
  for (int m = 0; m < 4; ++m)
#pragma unroll
    for (int nf = 0; nf < 3; ++nf)
#pragma unroll
      for (int r = 0; r < 4; ++r) {
        int row = m * 16 + (lane >> 4) * 4 + r;
        int col = w * 48 + nf * 16 + (lane & 15);
        out[(size_t)(row0 + row) * 384 + col] =
            f2bf(elup1(acc[m][nf][r] + bc[nf]));
      }
}

// ====== K1b: weight prep for 384-col weights (frag-major bf16 hi/lo) =====
// layout: [kstep 8][nfg 24][lane 64][j 8]; elem = W[k*384 + col],
// col = nfg*16+(l&15), k = kstep*32+(l>>4)*8+j.
__global__ __launch_bounds__(256) void prep_w384_kernel(
    const float* __restrict__ W, unsigned short* __restrict__ hi,
    unsigned short* __restrict__ lo) {
  int idx = blockIdx.x * 256 + threadIdx.x;  // < 98304
  int j = idx & 7, l = (idx >> 3) & 63, g = idx >> 9;  // g < 192
  int kstep = g / 24, nfg = g - kstep * 24;
  int col = nfg * 16 + (l & 15);
  int k = kstep * 32 + (l >> 4) * 8 + j;
  float v = W[k * 384 + col];
  unsigned short h = f2bf(v);
  hi[idx] = h;
  lo[idx] = f2bf(v - bf2f(h));
}

// ============ K2: spatial gram A[n,s,v,u] += sum_{t,c} q*k ===============
// LDS row stride padded 384 -> 390 (mod 32 = 6): k-operand reads across
// pu=0..24 hit >=16 distinct banks (worst 2-way, free).
constexpr int PJ_ = 390;  // padded LDS row stride (floats)
__global__ __launch_bounds__(256) void spatial_A_kernel(
    const unsigned short* __restrict__ QK, float* __restrict__ A) {
  __shared__ __align__(16) float qk[V_ * PJ_];  // 39.0 KB
  const int n = blockIdx.x >> 3, tq = blockIdx.x & 7;
  const int tid = threadIdx.x;
  float acc[3][3];
#pragma unroll
  for (int i = 0; i < 3; ++i)
#pragma unroll
    for (int s = 0; s < 3; ++s) acc[i][s] = 0.f;
  int pv[3], pu[3];
#pragma unroll
  for (int i = 0; i < 3; ++i) {
    int p = tid + 256 * i;
    pv[i] = p / V_;
    pu[i] = p - V_ * pv[i];
  }
  for (int tt = 0; tt < 16; ++tt) {
    int t = tq * 16 + tt;
    const ushort4* src4 =
        (const ushort4*)(QK + (size_t)(n * T_ + t) * (V_ * J_));
    __syncthreads();
    for (int i = tid; i < V_ * J_ / 4; i += 256) {
      int row = i / 96, wi = i - row * 96;  // 96 = J_/4
      ushort4 u = src4[i];
      float* d = qk + row * PJ_ + wi * 4;
      d[0] = bf2f(u.x);
      d[1] = bf2f(u.y);
      d[2] = bf2f(u.z);
      d[3] = bf2f(u.w);
    }
    __syncthreads();
#pragma unroll
    for (int i = 0; i < 3; ++i) {
      if (tid + 256 * i < 625) {
        const float* qr = qk + pv[i] * PJ_;
        const float* kr = qk + pu[i] * PJ_;
        for (int c = 0; c < 64; ++c) {
          float2 q01 = *(const float2*)(qr + c * 6);
          float q2 = qr[c * 6 + 2];
          float k0 = kr[c * 6 + 3];
          float2 k12 = *(const float2*)(kr + c * 6 + 4);
          acc[i][0] = fmaf(q01.x, k0, acc[i][0]);
          acc[i][1] = fmaf(q01.y, k12.x, acc[i][1]);
          acc[i][2] = fmaf(q2, k12.y, acc[i][2]);
        }
      }
    }
  }
#pragma unroll
  for (int i = 0; i < 3; ++i)
    if (tid + 256 * i < 625) {
#pragma unroll
      for (int s = 0; s < 3; ++s)
        atomicAdd(&A[((n * S_ + s) * V_ + pv[i]) * V_ + pu[i]], acc[i][s]);
    }
}

// ======= K3: A = A / rowsum + att0 ========================================
__global__ __launch_bounds__(64) void norm_A_kernel(
    float* __restrict__ A, const float* __restrict__ att0) {
  const int row = blockIdx.x;           // (n*S+s)*V + v
  const int sv = row % (S_ * V_);       // s*V + v
  const int lane = threadIdx.x;
  float val = (lane < V_) ? A[row * V_ + lane] : 0.f;
  float sum = wave_sum(val);
  if (lane < V_) A[row * V_ + lane] = val / sum + att0[sv * V_ + lane];
}

// ====== K4a: y768[nt, v, s, c] = bf16(sum_u A[n,s,v,u] * x[nt,u,c]) ======
__global__ __launch_bounds__(256) void y768_kernel(
    const float* __restrict__ X, const float* __restrict__ A,
    unsigned short* __restrict__ Y768) {
  __shared__ __align__(16) float xs[2 * VC_];      // 51.2 KB
  __shared__ __align__(16) float As[S_ * V_ * 28]; // padded rows
  const int nt0 = blockIdx.x * 2;
  const int n = nt0 >> 7;
  const int tid = threadIdx.x;  // = c
  for (int i = tid; i < 2 * VC_; i += 256)
    xs[i] = X[(size_t)nt0 * VC_ + i];
  const float* Abase = A + n * (S_ * V_ * V_);
  for (int i = tid; i < S_ * V_ * V_; i += 256) {
    int r = i / V_, u = i - r * V_;
    As[r * 28 + u] = Abase[i];
  }
  __syncthreads();
  float xu0[V_], xu1[V_];
#pragma unroll
  for (int u = 0; u < V_; ++u) {
    xu0[u] = xs[u * C_ + tid];
    xu1[u] = xs[VC_ + u * C_ + tid];
  }
  unsigned short* Ob0 = Y768 + (size_t)nt0 * (V_ * SC_);
  unsigned short* Ob1 = Ob0 + (V_ * SC_);
  for (int v = 0; v < V_; ++v) {
#pragma unroll
    for (int s = 0; s < 3; ++s) {
      const float* Ar = As + (s * V_ + v) * 28;
      float a0 = 0.f, a1 = 0.f;
#pragma unroll
      for (int u = 0; u < V_; ++u) {
        float av = Ar[u];
        a0 = fmaf(av, xu0[u], a0);
        a1 = fmaf(av, xu1[u], a1);
      }
      Ob0[(v * S_ + s) * C_ + tid] = f2bf(a0);
      Ob1[(v * S_ + s) * C_ + tid] = f2bf(a1);
    }
  }
}

// ====== K5: weight prep — fragment-major bf16 hi/lo (256-col weights) ====
__global__ __launch_bounds__(256) void prep_w_kernel(
    const float* __restrict__ W, int nS, unsigned short* __restrict__ hi,
    unsigned short* __restrict__ lo) {
  int idx = blockIdx.x * 256 + threadIdx.x;
  int j = idx & 7, l = (idx >> 3) & 63, nfg = (idx >> 9) & 15,
      kstep = (idx >> 13) & 7, s = idx >> 16;
  int col = nfg * 16 + (l & 15);
  int k = kstep * 32 + (l >> 4) * 8 + j;
  float v = W[(k * nS + s) * 256 + col];
  unsigned short h = f2bf(v);
  hi[idx] = h;
  lo[idx] = f2bf(v - bf2f(h));
}

// ====== MFMA projection kernel (8 waves / 512 threads) ===================
// MODE 0: spatial_out  g=gelu(X+ln(Y768@Wo+bo)); out=gelu(X+ln(g@Wf+bf)) f32
// MODE 1: proj_f       out = bf16(ln(Z@Wo+bo))
// MODE 2: proj_final_b g=gelu(Y+Pf+ln(Z@Wo+bo)); out=gelu(Y+ln(g@Wt+bt)) f32
// A-tile staging via global_load_lds (zero VGPRs held), K staged in
// 128-chunks, LDS double-buffered; single B buffer with in-phase
// load-ahead-by-one; LN stats inline from Red. VGPR 128, no scratch (r8).
#define LOADB_(dh, dl, Wh, Wl, sk)                                         \
  {                                                                        \
    _Pragma("unroll") for (int nf_ = 0; nf_ < 4; ++nf_) {                  \
      int wo_ = ((sk) * 16 + (wc * 4 + nf_)) * 512 + lane * 8;             \
      dh[nf_] = *(const bf16x8*)((Wh) + wo_);                              \
      dl[nf_] = *(const bf16x8*)((Wl) + wo_);                              \
    }                                                                      \
  }

// GEMM1 MFMA step: ks in [0,4), reads chunk (ks*8 + wr*4+m) of `buf`.
#define MFMA1_(ks, BH, BL)                                                 \
  {                                                                        \
    _Pragma("unroll") for (int m_ = 0; m_ < 4; ++m_) {                     \
      bf16x8 af_ = *(const bf16x8*)&buf[(((ks) * 8 + (wr * 4 + m_)) * 64 + \
                                        lane) * 8];                        \
      _Pragma("unroll") for (int nf_ = 0; nf_ < 4; ++nf_) {                \
        acc[m_][nf_] = __builtin_amdgcn_mfma_f32_16x16x32_bf16(            \
            af_, BH[nf_], acc[m_][nf_], 0, 0, 0);                          \
        acc[m_][nf_] = __builtin_amdgcn_mfma_f32_16x16x32_bf16(            \
            af_, BL[nf_], acc[m_][nf_], 0, 0, 0);                          \
      }                                                                    \
    }                                                                      \
  }

#define MFMA2_(ks, BH, BL)                                                 \
  {                                                                        \
    _Pragma("unroll") for (int m_ = 0; m_ < 4; ++m_) {                     \
      int row_ = wr * 64 + m_ * 16 + (lane & 15);                          \
      int slot_ = ((ks) * 4 + (lane >> 4)) ^ (row_ & 7);                   \
      bf16x8 af_ =                                                         \
          *(const bf16x8*)((const char*)Gsh + row_ * 512 + slot_ * 16);    \
      _Pragma("unroll") for (int nf_ = 0; nf_ < 4; ++nf_) {                \
        acc[m_][nf_] = __builtin_amdgcn_mfma_f32_16x16x32_bf16(            \
            af_, BH[nf_], acc[m_][nf_], 0, 0, 0);                          \
        acc[m_][nf_] = __builtin_amdgcn_mfma_f32_16x16x32_bf16(            \
            af_, BL[nf_], acc[m_][nf_], 0, 0, 0);                          \
      }                                                                    \
    }                                                                      \
  }

template <int MODE>
__global__ __launch_bounds__(512, 2) void mfma_proj_kernel(
    const unsigned short* __restrict__ A,    // bf16 GEMM1 input
    const unsigned short* __restrict__ W1h, const unsigned short* __restrict__ W1l,
    const float* __restrict__ b1,
    const float* __restrict__ Res,           // fp32 residual (X or y2)
    const unsigned short* __restrict__ Pf,   // bf16 (MODE 2)
    const unsigned short* __restrict__ W2h, const unsigned short* __restrict__ W2l,
    const float* __restrict__ b2,
    float* __restrict__ OutF,                // MODE 0/2
    unsigned short* __restrict__ OutB) {     // MODE 1
  __shared__ __align__(16) unsigned short Ash[2][16384];  // 2 x 32 KB A-tile bufs
  __shared__ __align__(16) float Red[128][8];             // 4 KB LN partials
  unsigned short* Gsh = &Ash[0][0];                       // 64 KB flat for G
  const int tid = threadIdx.x, lane = tid & 63, w = tid >> 6;
  const int wr = w >> 2, wc = w & 3;
  const int bid = blockIdx.x;
  const int n = bid / 25, mt = bid - n * 25;
  const int row0 = n * 3200 + mt * 128;  // flat row (nt*25+v) for Res/Pf/Out
  size_t abase, asstride;
  int arstride;
  if (MODE == 0) {  // Y768: [flat_row][s*256 + c], row stride 768
    abase = (size_t)row0 * 768; arstride = 768; asstride = 256;
  } else {          // Z: [n][s][flat_tv][c]
    abase = (size_t)n * ((size_t)S_ * T_ * VC_) + (size_t)(mt * 128) * 256;
    arstride = 256; asstride = (size_t)T_ * VC_;
  }

  // issue one K=128 stage (32 chunks of 1 KB) via global_load_lds: chunk
  // c = ks*8+mg; lane reads row mg*16+(lane&15), k = ks*32+(lane>>4)*8 (+base)
  auto stage_loads = [&](int t) {
    const int sblk = t >> 1;
    const int kbase = (t & 1) * 128;
#pragma unroll
    for (int i = 0; i < 4; ++i) {
      int c = w * 4 + i;
      int ks = c >> 3, mg = c & 7;
      int row = mg * 16 + (lane & 15);
      int koff = kbase + ks * 32 + (lane >> 4) * 8;
      const unsigned short* src = A + abase + (size_t)sblk * asstride +
                                  (size_t)row * arstride + koff;
      __builtin_amdgcn_global_load_lds(
          (const __attribute__((address_space(1))) unsigned int*)src,
          (__attribute__((address_space(3))) unsigned int*)&Ash[t & 1][c * 512],
          16, 0, 0);
    }
  };

  f32x4 acc[4][4];
#pragma unroll
  for (int m = 0; m < 4; ++m)
#pragma unroll
    for (int nf = 0; nf < 4; ++nf) acc[m][nf] = (f32x4){0.f, 0.f, 0.f, 0.f};

  bf16x8 bh[4], bl[4];

  // ---------------- GEMM1: K = 768 as 6 stages of 128 ----------------
  stage_loads(0);
  __syncthreads();  // drain stage-0 loads
  for (int t = 0; t < 6; ++t) {
    if (t < 5) stage_loads(t + 1);
    const unsigned short* buf = &Ash[t & 1][0];
    LOADB_(bh, bl, W1h, W1l, t * 4);
#pragma unroll
    for (int ks = 0; ks < 4; ++ks) {
      MFMA1_(ks, bh, bl);
      if (ks < 3) LOADB_(bh, bl, W1h, W1l, t * 4 + ks + 1);
    }
    __syncthreads();  // drains next-stage loads; releases buf for t+2
  }

  // ---------------- Epilogue 1: per-row LayerNorm stats ----------------
  float b1c[4];
#pragma unroll
  for (int nf = 0; nf < 4; ++nf) b1c[nf] = b1[wc * 64 + nf * 16 + (lane & 15)];
#pragma unroll
  for (int m = 0; m < 4; ++m)
#pragma unroll
    for (int r = 0; r < 4; ++r) {
      float su = 0.f, sq = 0.f;
#pragma unroll
      for (int nf = 0; nf < 4; ++nf) {
        float v = acc[m][nf][r] + b1c[nf];
        su += v; sq += v * v;
      }
#pragma unroll
      for (int off = 1; off < 16; off <<= 1) {
        su += __shfl_xor(su, off, 64);
        sq += __shfl_xor(sq, off, 64);
      }
      if ((lane & 15) == 0) {
        int row = wr * 64 + m * 16 + (lane >> 4) * 4 + r;
        Red[row][2 * wc + 0] = su;
        Red[row][2 * wc + 1] = sq;
      }
    }
  __syncthreads();

  if (MODE == 1) {  // proj_f: out = bf16(ln(vals))
#pragma unroll
    for (int m = 0; m < 4; ++m)
#pragma unroll
      for (int r = 0; r < 4; ++r) {
        int row = wr * 64 + m * 16 + (lane >> 4) * 4 + r;
        f32x4 p0 = *(const f32x4*)&Red[row][0];
        f32x4 p1 = *(const f32x4*)&Red[row][4];
        float mu = (p0.x + p0.z + p1.x + p1.z) * (1.f / 256.f);
        float sq = (p0.y + p0.w + p1.y + p1.w) * (1.f / 256.f);
        float rsd = rsqrtf(fmaxf(sq - mu * mu, 0.f) + 1e-5f);
#pragma unroll
        for (int nf = 0; nf < 4; ++nf) {
          int col = wc * 64 + nf * 16 + (lane & 15);
          OutB[(size_t)(row0 + row) * 256 + col] =
              f2bf((acc[m][nf][r] + b1c[nf] - mu) * rsd);
        }
      }
    return;
  }

  // g = gelu(res [+pf] + ln(vals)) -> bf16 in XOR-swizzled LDS (reuses Ash)
#pragma unroll
  for (int m = 0; m < 4; ++m)
#pragma unroll
    for (int r = 0; r < 4; ++r) {
      int row = wr * 64 + m * 16 + (lane >> 4) * 4 + r;
      f32x4 p0 = *(const f32x4*)&Red[row][0];
      f32x4 p1 = *(const f32x4*)&Red[row][4];
      float mu = (p0.x + p0.z + p1.x + p1.z) * (1.f / 256.f);
      float sq = (p0.y + p0.w + p1.y + p1.w) * (1.f / 256.f);
      float rsd = rsqrtf(fmaxf(sq - mu * mu, 0.f) + 1e-5f);
#pragma unroll
      for (int nf = 0; nf < 4; ++nf) {
        int col = wc * 64 + nf * 16 + (lane & 15);
        float resv = Res[(size_t)(row0 + row) * 256 + col];
        if (MODE == 2) resv += bf2f(Pf[(size_t)(row0 + row) * 256 + col]);
        float gv = gelu_f(resv + (acc[m][nf][r] + b1c[nf] - mu) * rsd);
        int slot = (col >> 3) ^ (row & 7);
        *(unsigned short*)((char*)Gsh + row * 512 + slot * 16 + (col & 7) * 2) =
            f2bf(gv);
      }
    }
  __syncthreads();

  // ---------------- GEMM2: K = 256 from Gsh ----------------
#pragma unroll
  for (int m = 0; m < 4; ++m)
#pragma unroll
    for (int nf = 0; nf < 4; ++nf) acc[m][nf] = (f32x4){0.f, 0.f, 0.f, 0.f};
  LOADB_(bh, bl, W2h, W2l, 0);
#pragma unroll 2
  for (int ks = 0; ks < 8; ++ks) {
    MFMA2_(ks, bh, bl);
    if (ks < 7) LOADB_(bh, bl, W2h, W2l, ks + 1);
  }

  // ---------------- Epilogue 2 ----------------
  float b2c[4];
#pragma unroll
  for (int nf = 0; nf < 4; ++nf) b2c[nf] = b2[wc * 64 + nf * 16 + (lane & 15)];
  __syncthreads();  // Red reads of epilogue 1 done everywhere
#pragma unroll
  for (int m = 0; m < 4; ++m)
#pragma unroll
    for (int r = 0; r < 4; ++r) {
      float su = 0.f, sq = 0.f;
#pragma unroll
      for (int nf = 0; nf < 4; ++nf) {
        float v = acc[m][nf][r] + b2c[nf];
        su += v; sq += v * v;
      }
#pragma unroll
      for (int off = 1; off < 16; off <<= 1) {
        su += __shfl_xor(su, off, 64);
        sq += __shfl_xor(sq, off, 64);
      }
      if ((lane & 15) == 0) {
        int row = wr * 64 + m * 16 + (lane >> 4) * 4 + r;
        Red[row][2 * wc + 0] = su;
        Red[row][2 * wc + 1] = sq;
      }
    }
  __syncthreads();
#pragma unroll
  for (int m = 0; m < 4; ++m)
#pragma unroll
    for (int r = 0; r < 4; ++r) {
      int row = wr * 64 + m * 16 + (lane >> 4) * 4 + r;
      f32x4 p0 = *(const f32x4*)&Red[row][0];
      f32x4 p1 = *(const f32x4*)&Red[row][4];
      float mu = (p0.x + p0.z + p1.x + p1.z) * (1.f / 256.f);
      float sq = (p0.y + p0.w + p1.y + p1.w) * (1.f / 256.f);
      float rsd = rsqrtf(fmaxf(sq - mu * mu, 0.f) + 1e-5f);
#pragma unroll
      for (int nf = 0; nf < 4; ++nf) {
        int col = wc * 64 + nf * 16 + (lane & 15);
        float resv = Res[(size_t)(row0 + row) * 256 + col];
        OutF[(size_t)(row0 + row) * 256 + col] =
            gelu_f(resv + (acc[m][nf][r] + b2c[nf] - mu) * rsd);
      }
    }
}

// ====== K6: Af[n,s,t,k] = sum_{v,c} q[t]*k[k]  (unnormalized) ============
__global__ __launch_bounds__(256) void temporal_A_kernel(
    const unsigned short* __restrict__ QK, float* __restrict__ A) {
  __shared__ __align__(16) float Qs[32 * 68];
  __shared__ __align__(16) float Ks[128 * 68];
  const int tt = blockIdx.x, s = blockIdx.y, n = blockIdx.z;
  const int tid = threadIdx.x;
  const int kg = tid & 15;   // k = kg + 16*j
  const int tp = tid >> 4;   // rows tp*2, tp*2+1
  float acc[2][8];
#pragma unroll
  for (int r = 0; r < 2; ++r)
#pragma unroll
    for (int j = 0; j < 8; ++j) acc[r][j] = 0.f;
  for (int v = 0; v < V_; ++v) {
    __syncthreads();
    for (int i = tid; i < 128 * 64; i += 256) {
      int k = i >> 6, c = i & 63;
      Ks[k * 68 + c] =
          bf2f(QK[(size_t)((n * T_ + k) * V_ + v) * J_ + c * 6 + 3 + s]);
    }
    for (int i = tid; i < 32 * 64; i += 256) {
      int t = i >> 6, c = i & 63;
      Qs[t * 68 + c] =
          bf2f(QK[(size_t)((n * T_ + tt * 32 + t) * V_ + v) * J_ + c * 6 + s]);
    }
    __syncthreads();
    for (int c = 0; c < 64; c += 4) {
      float4 q0 = *(const float4*)(Qs + (tp * 2 + 0) * 68 + c);
      float4 q1 = *(const float4*)(Qs + (tp * 2 + 1) * 68 + c);
#pragma unroll
      for (int j = 0; j < 8; ++j) {
        float4 kv = *(const float4*)(Ks + (kg + 16 * j) * 68 + c);
        acc[0][j] = fmaf(q0.x, kv.x, fmaf(q0.y, kv.y,
                    fmaf(q0.z, kv.z, fmaf(q0.w, kv.w, acc[0][j]))));
        acc[1][j] = fmaf(q1.x, kv.x, fmaf(q1.y, kv.y,
                    fmaf(q1.z, kv.z, fmaf(q1.w, kv.w, acc[1][j]))));
      }
    }
  }
  float* Ob = A + ((size_t)(n * S_ + s) * T_ + tt * 32) * T_;
#pragma unroll
  for (int r = 0; r < 2; ++r)
#pragma unroll
    for (int j = 0; j < 8; ++j)
      Ob[(tp * 2 + r) * T_ + kg + 16 * j] = acc[r][j];
}

// ====== K6b: mask (tril/triu) + row-normalize Af and Ab ==================
__global__ __launch_bounds__(64) void norm_temporal_kernel(
    float* __restrict__ Af, float* __restrict__ Ab) {
  const int row = blockIdx.x;  // (n*S+s)*T + t
  const int t = row & (T_ - 1);
  const int lane = threadIdx.x;
  float* A = blockIdx.y == 0 ? Af : Ab;
  const bool fw = blockIdx.y == 0;
  float v0 = A[(size_t)row * T_ + lane];
  float v1 = A[(size_t)row * T_ + lane + 64];
  v0 *= fw ? (lane <= t ? 1.f : 0.f) : (lane >= t ? 1.f : 0.f);
  v1 *= fw ? (lane + 64 <= t ? 1.f : 0.f) : (lane + 64 >= t ? 1.f : 0.f);
  float inv = 1.f / wave_sum(v0 + v1);
  A[(size_t)row * T_ + lane] = v0 * inv;
  A[(size_t)row * T_ + lane + 64] = v1 * inv;
}

// ====== K7: Z[n,s,t,vc] = bf16(sum_k A[n,s,t,k] * Y[n,k,vc]) — MFMA ======
__global__ __launch_bounds__(256, 3) void temporal_z_mfma_kernel(
    const float* __restrict__ A, const float* __restrict__ Y,
    unsigned short* __restrict__ Z) {
  __shared__ __align__(16) unsigned short Ahs[4 * 4 * 64 * 8];  // 16 KB
  __shared__ __align__(16) unsigned short Als[4 * 4 * 64 * 8];  // 16 KB
  __shared__ __align__(16) unsigned short Ys[16 * 64 * 8];      // 16 KB
  const int cb = blockIdx.x;                     // col block of 256
  const int s = blockIdx.y >> 1, rt = blockIdx.y & 1;
  const int n = blockIdx.z;
  const int tid = threadIdx.x, lane = tid & 63, w = tid >> 6;
  const int t0 = rt * 64;
  const float* Atile = A + ((size_t)(n * S_ + s) * T_ + t0) * T_;  // 64x128
  // convert A tile to frag-major bf16 hi/lo
  for (int i = tid; i < 64 * 128; i += 256) {
    int r = i >> 7, k = i & 127;
    float av = Atile[r * T_ + k];
    unsigned short h = f2bf(av);
    unsigned short l = f2bf(av - bf2f(h));
    int idx = ((((k >> 5) * 4 + (r >> 4)) * 64 + (r & 15) + 16 * ((k >> 3) & 3))
               << 3) | (k & 7);
    Ahs[idx] = h;
    Als[idx] = l;
  }
  f32x4 acc[4][4];
#pragma unroll
  for (int m = 0; m < 4; ++m)
#pragma unroll
    for (int nf = 0; nf < 4; ++nf) acc[m][nf] = (f32x4){0.f, 0.f, 0.f, 0.f};
  const float* Yb = Y + (size_t)n * (T_ * VC_) + cb * 256;
  for (int kstep = 0; kstep < 4; ++kstep) {
    __syncthreads();  // A-conversion done (iter 0) / prior Ys reads done
    for (int i = tid; i < 32 * 256; i += 256) {
      int kl = i >> 8, c = i & 255;
      float yv = Yb[(size_t)(kstep * 32 + kl) * VC_ + c];
      Ys[(((c >> 4) * 64 + (c & 15) + 16 * ((kl >> 3) & 3)) << 3) | (kl & 7)] =
          f2bf(yv);
    }
    __syncthreads();
    bf16x8 bv[4];
#pragma unroll
    for (int nf = 0; nf < 4; ++nf)
      bv[nf] = *(const bf16x8*)&Ys[((w * 4 + nf) * 64 + lane) * 8];
    bf16x8 af[4];
#pragma unroll
    for (int m = 0; m < 4; ++m)
      af[m] = *(const bf16x8*)&Ahs[((kstep * 4 + m) * 64 + lane) * 8];
#pragma unroll
    for (int nf = 0; nf < 4; ++nf)
#pragma unroll
      for (int m = 0; m < 4; ++m)
        acc[m][nf] = __builtin_amdgcn_mfma_f32_16x16x32_bf16(af[m], bv[nf], acc[m][nf], 0, 0, 0);
#pragma unroll
    for (int m = 0; m < 4; ++m)
      af[m] = *(const bf16x8*)&Als[((kstep * 4 + m) * 64 + lane) * 8];
#pragma unroll
    for (int nf = 0; nf < 4; ++nf)
#pragma unroll
      for (int m = 0; m < 4; ++m)
        acc[m][nf] = __builtin_amdgcn_mfma_f32_16x16x32_bf16(af[m], bv[nf], acc[m][nf], 0, 0, 0);
  }
  unsigned short* Zb = Z + ((size_t)(n * S_ + s) * T_ + t0) * VC_ + cb * 256;
#pragma unroll
  for (int m = 0; m < 4; ++m)
#pragma unroll
    for (int nf = 0; nf < 4; ++nf)
#pragma unroll
      for (int r = 0; r < 4; ++r) {
        int trow = m * 16 + (lane >> 4) * 4 + r;
        int col = w * 64 + nf * 16 + (lane & 15);
        Zb[(size_t)trow * VC_ + col] = f2bf(acc[m][nf][r]);
      }
}

extern "C" void kernel_launch(void* const* d_in, const int* in_sizes, int n_in,
                              void* d_out, int out_size, void* d_ws,
                              size_t ws_size, hipStream_t stream) {
  const float* x      = (const float*)d_in[0];
  const float* W_ins  = (const float*)d_in[1];
  const float* b_ins  = (const float*)d_in[2];
  const float* att0   = (const float*)d_in[3];
  const float* W_outs = (const float*)d_in[4];
  const float* b_outs = (const float*)d_in[5];
  const float* W_ffs  = (const float*)d_in[6];
  const float* b_ffs  = (const float*)d_in[7];
  const float* W_inf  = (const float*)d_in[8];
  const float* b_inf  = (const float*)d_in[9];
  const float* W_inb  = (const float*)d_in[10];
  const float* b_inb  = (const float*)d_in[11];
  const float* W_outf = (const float*)d_in[12];
  const float* b_outf = (const float*)d_in[13];
  const float* W_outb = (const float*)d_in[14];
  const float* b_outb = (const float*)d_in[15];
  const float* W_fft  = (const float*)d_in[16];
  const float* b_fft  = (const float*)d_in[17];
  float* out = (float*)d_out;
  char* base = (char*)d_ws;

  // Workspace layout (bytes). Peak ≈ 658,854,656 B ≈ 628.3 MiB.
  unsigned short* B0    = (unsigned short*)base;
  float*          y2    = (float*)(base + 314572800);           // 209.7 MB fp32
  unsigned short* projf = (unsigned short*)(base + 524288000);  // 104.9 MB bf16
  float*          Asp   = (float*)(base + 629145600);           // 0.48 MB
  float*          Af    = (float*)(base + 629625600);           // 12.6 MB
  float*          Ab    = (float*)(base + 642208512);           // 12.6 MB
  unsigned short* Wouts_h = (unsigned short*)(base + 654791424);
  unsigned short* Wouts_l = (unsigned short*)(base + 655184640);
  unsigned short* Wffs_h  = (unsigned short*)(base + 655577856);
  unsigned short* Wffs_l  = (unsigned short*)(base + 655708928);
  unsigned short* Woutf_h = (unsigned short*)(base + 655840000);
  unsigned short* Woutf_l = (unsigned short*)(base + 656233216);
  unsigned short* Woutb_h = (unsigned short*)(base + 656626432);
  unsigned short* Woutb_l = (unsigned short*)(base + 657019648);
  unsigned short* Wfft_h  = (unsigned short*)(base + 657412864);
  unsigned short* Wfft_l  = (unsigned short*)(base + 657543936);
  // 384-col weight prep (new, 6 x 192 KB = 1.13 MB)
  unsigned short* Wins_h  = (unsigned short*)(base + 657675008);
  unsigned short* Wins_l  = (unsigned short*)(base + 657871616);
  unsigned short* Winf_h  = (unsigned short*)(base + 658068224);
  unsigned short* Winf_l  = (unsigned short*)(base + 658264832);
  unsigned short* Winb_h  = (unsigned short*)(base + 658461440);
  unsigned short* Winb_l  = (unsigned short*)(base + 658658048);

  unsigned short* QKs  = B0;
  unsigned short* Y768 = B0;
  unsigned short* QKf  = B0;
  unsigned short* QKb  = B0 + 78643200;
  unsigned short* Zbuf = B0;

  // ---- weight prep (fragment-major bf16 hi/lo) ----
  prep_w_kernel<<<768, 256, 0, stream>>>(W_outs, 3, Wouts_h, Wouts_l);
  prep_w_kernel<<<256, 256, 0, stream>>>(W_ffs, 1, Wffs_h, Wffs_l);
  prep_w_kernel<<<768, 256, 0, stream>>>(W_outf, 3, Woutf_h, Woutf_l);
  prep_w_kernel<<<768, 256, 0, stream>>>(W_outb, 3, Woutb_h, Woutb_l);
  prep_w_kernel<<<256, 256, 0, stream>>>(W_fft, 1, Wfft_h, Wfft_l);
  prep_w384_kernel<<<384, 256, 0, stream>>>(W_ins, Wins_h, Wins_l);
  prep_w384_kernel<<<384, 256, 0, stream>>>(W_inf, Winf_h, Winf_l);
  prep_w384_kernel<<<384, 256, 0, stream>>>(W_inb, Winb_h, Winb_l);

  // ---- spatial stage ----
  gemm_in_mfma_kernel<<<3200, 512, 0, stream>>>(x, Wins_h, Wins_l, b_ins, QKs);
  hipMemsetAsync(Asp, 0, (size_t)N_ * S_ * V_ * V_ * sizeof(float), stream);
  spatial_A_kernel<<<N_ * 8, 256, 0, stream>>>(QKs, Asp);
  norm_A_kernel<<<N_ * S_ * V_, 64, 0, stream>>>(Asp, att0);
  y768_kernel<<<NT_ / 2, 256, 0, stream>>>(x, Asp, Y768);
  mfma_proj_kernel<0><<<1600, 512, 0, stream>>>(
      Y768, Wouts_h, Wouts_l, b_outs, x, nullptr, Wffs_h, Wffs_l, b_ffs, y2,
      nullptr);
  // ---- temporal stage ----
  gemm_in_mfma_kernel<<<3200, 512, 0, stream>>>(y2, Winf_h, Winf_l, b_inf, QKf);
  gemm_in_mfma_kernel<<<3200, 512, 0, stream>>>(y2, Winb_h, Winb_l, b_inb, QKb);
  temporal_A_kernel<<<dim3(4, 3, 64), 256, 0, stream>>>(QKf, Af);
  temporal_A_kernel<<<dim3(4, 3, 64), 256, 0, stream>>>(QKb, Ab);
  norm_temporal_kernel<<<dim3(N_ * S_ * T_, 2), 64, 0, stream>>>(Af, Ab);
  // forward: Zf -> projf (Zbuf overlays dead QKf/QKb)
  temporal_z_mfma_kernel<<<dim3(25, 6, 64), 256, 0, stream>>>(Af, y2, Zbuf);
  mfma_proj_kernel<1><<<1600, 512, 0, stream>>>(
      Zbuf, Woutf_h, Woutf_l, b_outf, nullptr, nullptr, nullptr, nullptr,
      nullptr, nullptr, projf);
  // backward: Zb -> fused projection + final output
  temporal_z_mfma_kernel<<<dim3(25, 6, 64), 256, 0, stream>>>(Ab, y2, Zbuf);
  mfma_proj_kernel<2><<<1600, 512, 0, stream>>>(
      Zbuf, Woutb_h, Woutb_l, b_outb, y2, projf, Wfft_h, Wfft_l, b_fft, out,
      nullptr);
}